// Round 6
// baseline (213.592 us; speedup 1.0000x reference)
//
#include <hip/hip_runtime.h>
#include <hip/hip_bf16.h>
#include <stdint.h>

// Problem constants (from reference)
#define B_  2
#define F_  2
#define C_  64
#define D_  96
#define HM_ 48
#define WM_ 160
#define HW_ (HM_ * WM_)                 // 7680
#define NTOT ((size_t)B_ * D_ * HW_)    // 1,474,560 per output tensor
#define EPS_ 1e-7f
#define DG_  8                          // depths per thread
#define NDG_ (D_ / DG_)                 // 12 depth groups

typedef _Float16 h2 __attribute__((ext_vector_type(2)));
struct QuadH { h2 r0, r1; };            // 8B: (v00,v01),(v10,v11) as f16

#if __has_builtin(__builtin_amdgcn_fdot2)
__device__ __forceinline__ float FDOT2(h2 a, h2 b, float c) {
    return __builtin_amdgcn_fdot2(a, b, c, false);
}
#else
__device__ __forceinline__ float FDOT2(h2 a, h2 b, float c) {
    return (float)a.x * (float)b.x + (float)a.y * (float)b.y + c;
}
#endif

// ---------------------------------------------------------------------------
// Pack corner quads into chunk-interleaved layout:
//   quad[((n*8 + c8)*HW + pix)*8 + cl]   (n = b*F+f, c = c8*8+cl)
// so one pixel's 8-channel chunk is 64 contiguous bytes (one cache line).
// Also (block 0) computes P = (K@T)[:3] and pose validity.
// ---------------------------------------------------------------------------
__global__ __launch_bounds__(256) void pack_and_setup(
    const float* __restrict__ look,   // [B*F][C][HW]
    QuadH* __restrict__ quad,
    const float* __restrict__ poses,
    const float* __restrict__ K,
    float* __restrict__ Pout,         // [B*F][12]
    float* __restrict__ validOut)     // [B*F]
{
    if (blockIdx.x == 0 && threadIdx.x < 64) {
        int t = threadIdx.x;
        if (t < B_ * F_ * 12) {
            int j  = t & 3;
            int i  = (t >> 2) % 3;
            int bf = t / 12;
            int b  = bf / F_;
            const float* Kb = K + (size_t)b * 16;
            const float* T  = poses + (size_t)bf * 16;
            float s = 0.f;
            #pragma unroll
            for (int k = 0; k < 4; ++k) s += Kb[i * 4 + k] * T[k * 4 + j];
            Pout[bf * 12 + i * 4 + j] = s;
        }
        if (t < B_ * F_) {
            const float* T = poses + (size_t)t * 16;
            float s = 0.f;
            #pragma unroll
            for (int k = 0; k < 16; ++k) s += T[k];
            validOut[t] = (s != 0.0f) ? 1.0f : 0.0f;
        }
    }

    int t = blockIdx.x * 256 + threadIdx.x;   // exact: B*F*C*HW = 7680*256
    int cl   = t & 7;
    int rem  = t >> 3;
    int hw   = rem % HW_;
    int rem2 = rem / HW_;                     // n*8 + c8
    int c8   = rem2 & 7;
    int n    = rem2 >> 3;                     // b*F + f
    int c    = c8 * 8 + cl;

    int x = hw % WM_, y = hw / WM_;
    int x1 = min(x + 1, WM_ - 1), y1 = min(y + 1, HM_ - 1);
    const float* base = look + ((size_t)n * C_ + c) * HW_;
    float v00 = base[y  * WM_ + x];
    float v01 = base[y  * WM_ + x1];
    float v10 = base[y1 * WM_ + x];
    float v11 = base[y1 * WM_ + x1];
    QuadH q;
    q.r0 = h2{(_Float16)v00, (_Float16)v01};
    q.r1 = h2{(_Float16)v10, (_Float16)v11};
    quad[t] = q;
}

// ---------------------------------------------------------------------------
// Main cost-volume kernel. One thread = one pixel x 8 consecutive depths.
//  * cur's 64 channels live in registers for all 8 depths (÷8 cur traffic)
//  * consecutive depths' quad windows overlap -> L1 temporal hits
//  * inner loop: per 8-channel chunk, 4 dwordx4 loads at immediate offsets
//    (one 64B line per lane), FDOT2 math, no per-channel address arithmetic.
// ---------------------------------------------------------------------------
__global__ __launch_bounds__(256) void cost_volume(
    const float* __restrict__ cur,     // [B][C][HW]
    const QuadH* __restrict__ quad,    // chunk-interleaved (see pack)
    const float* __restrict__ invK,    // [B][16]
    const float* __restrict__ P,       // [B*F][12]
    const float* __restrict__ validF,  // [B*F]
    float* __restrict__ cvOut)         // [B][D][HW]
{
    int blk  = blockIdx.x;             // 720 = 30 tiles * (B*NDG)
    int tile = blk / (B_ * NDG_);
    int r    = blk % (B_ * NDG_);
    int b    = r / NDG_;
    int dg   = r % NDG_;
    int hw   = tile * 256 + threadIdx.x;

    int x = hw % WM_, y = hw / WM_;
    float fx = (float)x, fy = (float)y;

    const float* ik = invK + (size_t)b * 16;
    float rx = ik[0] * fx + ik[1] * fy + ik[2];
    float ry = ik[4] * fx + ik[5] * fy + ik[6];
    float rz = ik[8] * fx + ik[9] * fy + ik[10];

    bool inter = (x >= 2 && x <= WM_ - 3 && y >= 2 && y <= HM_ - 3);

    // Uniform per-frame projection rows (SGPRs) and per-thread ray dots
    float P0[12], P1[12];
    #pragma unroll
    for (int j = 0; j < 12; ++j) P0[j] = P[(b * F_ + 0) * 12 + j];
    #pragma unroll
    for (int j = 0; j < 12; ++j) P1[j] = P[(b * F_ + 1) * 12 + j];
    float pr00 = P0[0]*rx + P0[1]*ry + P0[2]*rz;
    float pr01 = P0[4]*rx + P0[5]*ry + P0[6]*rz;
    float pr02 = P0[8]*rx + P0[9]*ry + P0[10]*rz;
    float pr10 = P1[0]*rx + P1[1]*ry + P1[2]*rz;
    float pr11 = P1[4]*rx + P1[5]*ry + P1[6]*rz;
    float pr12 = P1[8]*rx + P1[9]*ry + P1[10]*rz;
    float vf0 = validF[b * F_ + 0], vf1 = validF[b * F_ + 1];

    // cur channels -> registers (constant indices via full unroll)
    float curv[C_];
    const float* cp = cur + (size_t)(b * C_ * HW_ + hw);
    #pragma unroll
    for (int c = 0; c < C_; ++c) curv[c] = cp[(size_t)c * HW_];

    const char* qbase = (const char*)quad;

    #pragma unroll 1
    for (int i = 0; i < DG_; ++i) {
        int d = dg * DG_ + i;
        float depth = 0.1f + (float)d * (19.9f / 95.0f);

        // frame 0 projection
        float cp00 = fmaf(depth, pr00, P0[3]);
        float cp01 = fmaf(depth, pr01, P0[7]);
        float cp02 = fmaf(depth, pr02, P0[11]);
        float z0 = cp02 + EPS_;
        float gx0 = cp00 / z0, gy0 = cp01 / z0;
        float x0f0 = floorf(gx0), y0f0 = floorf(gy0);
        float wx1_0 = gx0 - x0f0, wy1_0 = gy0 - y0f0;
        float wx0_0 = 1.f - wx1_0, wy0_0 = 1.f - wy1_0;
        int cx0 = min(max((int)x0f0, 0), WM_ - 1);
        int cy0 = min(max((int)y0f0, 0), HM_ - 1);
        unsigned pix0 = (unsigned)(cy0 * WM_ + cx0);
        h2 wA0 = h2{(_Float16)(wx0_0 * wy0_0), (_Float16)(wx1_0 * wy0_0)};
        h2 wB0 = h2{(_Float16)(wx0_0 * wy1_0), (_Float16)(wx1_0 * wy1_0)};
        bool e0 = (gx0 >= 2.f) && (gx0 <= (float)(WM_ - 2)) &&
                  (gy0 >= 2.f) && (gy0 <= (float)(HM_ - 2)) && inter;
        float ff0 = (e0 ? 1.f : 0.f) * vf0;

        // frame 1 projection
        float cp10 = fmaf(depth, pr10, P1[3]);
        float cp11 = fmaf(depth, pr11, P1[7]);
        float cp12 = fmaf(depth, pr12, P1[11]);
        float z1 = cp12 + EPS_;
        float gx1 = cp10 / z1, gy1 = cp11 / z1;
        float x0f1 = floorf(gx1), y0f1 = floorf(gy1);
        float wx1_1 = gx1 - x0f1, wy1_1 = gy1 - y0f1;
        float wx0_1 = 1.f - wx1_1, wy0_1 = 1.f - wy1_1;
        int cx1 = min(max((int)x0f1, 0), WM_ - 1);
        int cy1 = min(max((int)y0f1, 0), HM_ - 1);
        unsigned pix1 = (unsigned)(cy1 * WM_ + cx1);
        h2 wA1 = h2{(_Float16)(wx0_1 * wy0_1), (_Float16)(wx1_1 * wy0_1)};
        h2 wB1 = h2{(_Float16)(wx0_1 * wy1_1), (_Float16)(wx1_1 * wy1_1)};
        bool e1 = (gx1 >= 2.f) && (gx1 <= (float)(WM_ - 2)) &&
                  (gy1 >= 2.f) && (gy1 <= (float)(HM_ - 2)) && inter;
        float ff1 = (e1 ? 1.f : 0.f) * vf1;

        size_t oidx = ((size_t)(b * D_ + d)) * HW_ + hw;

        if (__ballot(ff0 > 0.f || ff1 > 0.f) == 0ull) {
            cvOut[oidx] = 0.f;
            continue;
        }

        float s0 = 0.f, s1 = 0.f;
        #pragma unroll
        for (int c8 = 0; c8 < 8; ++c8) {
            const char* p0 = qbase +
                (size_t)(((unsigned)((b * F_ + 0) * 8 + c8) * HW_ + pix0)) * 64u;
            const char* p1 = qbase +
                (size_t)(((unsigned)((b * F_ + 1) * 8 + c8) * HW_ + pix1)) * 64u;
            QuadH qs0[8], qs1[8];
            #pragma unroll
            for (int j = 0; j < 4; ++j) {
                ((uint4*)qs0)[j] = *((const uint4*)p0 + j);
                ((uint4*)qs1)[j] = *((const uint4*)p1 + j);
            }
            #pragma unroll
            for (int j = 0; j < 8; ++j) {
                float n = -curv[c8 * 8 + j];
                s0 += fabsf(FDOT2(qs0[j].r0, wA0, FDOT2(qs0[j].r1, wB0, n)));
                s1 += fabsf(FDOT2(qs1[j].r0, wA1, FDOT2(qs1[j].r1, wB1, n)));
            }
        }

        float m0 = s0 * (1.0f / 64.0f) * ff0;
        float m1 = s1 * (1.0f / 64.0f) * ff1;
        float costsum = m0 + m1;
        float counts  = ((m0 > 0.f) ? 1.f : 0.f) + ((m1 > 0.f) ? 1.f : 0.f);
        float scale = (counts > 1.5f) ? (1.0f / (2.0f + EPS_)) : (1.0f / (1.0f + EPS_));
        cvOut[oidx] = costsum * scale;
    }
}

// ---------------------------------------------------------------------------
// Finalize: per (b,hw), max over D, then write cost / missing.
// ---------------------------------------------------------------------------
__global__ __launch_bounds__(256) void finalize(
    const float* __restrict__ cv,   // [B][D][HW]
    float* __restrict__ cost,       // [B][D][HW]
    float* __restrict__ missing)    // [B][D][HW]
{
    int t = blockIdx.x * blockDim.x + threadIdx.x;
    if (t >= B_ * HW_) return;
    int b = t / HW_, hw = t % HW_;
    const float* src = cv + (size_t)b * D_ * HW_ + hw;

    float mx = 0.f;   // all values >= 0
    for (int d = 0; d < D_; ++d)
        mx = fmaxf(mx, src[(size_t)d * HW_]);

    for (int d = 0; d < D_; ++d) {
        float v = src[(size_t)d * HW_];
        float m = (v == 0.f) ? 1.f : 0.f;
        size_t o = (size_t)b * D_ * HW_ + (size_t)d * HW_ + hw;
        cost[o]    = (m != 0.f) ? mx : v;
        missing[o] = m;
    }
}

// ---------------------------------------------------------------------------
extern "C" void kernel_launch(void* const* d_in, const int* in_sizes, int n_in,
                              void* d_out, int out_size, void* d_ws, size_t ws_size,
                              hipStream_t stream)
{
    const float* current = (const float*)d_in[0];  // [B,C,H,W]
    const float* lookup  = (const float*)d_in[1];  // [B,F,C,H,W]
    const float* poses   = (const float*)d_in[2];  // [B,F,4,4]
    const float* K       = (const float*)d_in[3];  // [B,4,4]
    const float* invK    = (const float*)d_in[4];  // [B,4,4]

    float* out = (float*)d_out;
    float* costOut    = out;                 // [B,D,H,W]
    float* missingOut = out + NTOT;          // [B,D,H,W]
    float* cvOut      = out + 2 * NTOT;      // [B,D,H,W] (pre-fill cost)

    // workspace layout: small params first, then the 15.75 MB quad buffer
    float* ws     = (float*)d_ws;
    float* Pmat   = ws;                      // B*F*12 = 48 floats
    float* validF = Pmat + B_ * F_ * 12;     // B*F    = 4 floats
    QuadH* quad   = (QuadH*)(ws + 64);       // B*F*C*HW QuadH = 15,728,640 B

    const int nquad = B_ * F_ * C_ * HW_;        // 1,966,080 = 7680 * 256
    hipLaunchKernelGGL(pack_and_setup, dim3(nquad / 256), dim3(256), 0, stream,
                       lookup, quad, poses, K, Pmat, validF);

    const int nblocks = (HW_ / 256) * B_ * NDG_; // 30 * 24 = 720
    hipLaunchKernelGGL(cost_volume, dim3(nblocks), dim3(256), 0, stream,
                       current, quad, invK, Pmat, validF, cvOut);

    const int npix = B_ * HW_;                   // 15,360
    hipLaunchKernelGGL(finalize, dim3((npix + 255) / 256), dim3(256), 0, stream,
                       cvOut, costOut, missingOut);
}

// Round 7
// 184.212 us; speedup vs baseline: 1.1595x; 1.1595x over previous
//
#include <hip/hip_runtime.h>
#include <hip/hip_bf16.h>
#include <stdint.h>

// Problem constants (from reference)
#define B_  2
#define F_  2
#define C_  64
#define D_  96
#define HM_ 48
#define WM_ 160
#define HW_ (HM_ * WM_)                 // 7680
#define NTOT ((size_t)B_ * D_ * HW_)    // 1,474,560 per output tensor
#define EPS_ 1e-7f
#define DG_  4                          // depths per thread
#define NDG_ (D_ / DG_)                 // 24 depth groups

typedef _Float16 h2 __attribute__((ext_vector_type(2)));
struct QuadH { h2 r0, r1; };            // 8B: (v00,v01),(v10,v11) as f16

#if __has_builtin(__builtin_amdgcn_fdot2)
__device__ __forceinline__ float FDOT2(h2 a, h2 b, float c) {
    return __builtin_amdgcn_fdot2(a, b, c, false);
}
#else
__device__ __forceinline__ float FDOT2(h2 a, h2 b, float c) {
    return (float)a.x * (float)b.x + (float)a.y * (float)b.y + c;
}
#endif

// ---------------------------------------------------------------------------
// Pack corner quads, round-5 layout [n][C][HW] (8B per pixel, coalesced).
// Block 0 also computes P = (K@T)[:3] and pose validity.
// ---------------------------------------------------------------------------
__global__ __launch_bounds__(256) void pack_and_setup(
    const float* __restrict__ look,   // [B*F*C][HW]
    QuadH* __restrict__ quad,         // [B*F*C*HW]
    const float* __restrict__ poses,
    const float* __restrict__ K,
    float* __restrict__ Pout,         // [B*F][12]
    float* __restrict__ validOut)     // [B*F]
{
    if (blockIdx.x == 0 && threadIdx.x < 64) {
        int t = threadIdx.x;
        if (t < B_ * F_ * 12) {
            int j  = t & 3;
            int i  = (t >> 2) % 3;
            int bf = t / 12;
            int b  = bf / F_;
            const float* Kb = K + (size_t)b * 16;
            const float* T  = poses + (size_t)bf * 16;
            float s = 0.f;
            #pragma unroll
            for (int k = 0; k < 4; ++k) s += Kb[i * 4 + k] * T[k * 4 + j];
            Pout[bf * 12 + i * 4 + j] = s;
        }
        if (t < B_ * F_) {
            const float* T = poses + (size_t)t * 16;
            float s = 0.f;
            #pragma unroll
            for (int k = 0; k < 16; ++k) s += T[k];
            validOut[t] = (s != 0.0f) ? 1.0f : 0.0f;
        }
    }

    int t = blockIdx.x * 256 + threadIdx.x;   // exact: B*F*C*HW = 7680*256
    int hw = t % HW_;
    int n  = t / HW_;                          // (b*F+f)*C + c
    int x = hw % WM_, y = hw / WM_;
    int x1 = min(x + 1, WM_ - 1), y1 = min(y + 1, HM_ - 1);
    const float* base = look + (size_t)n * HW_;
    float v00 = base[y  * WM_ + x];
    float v01 = base[y  * WM_ + x1];
    float v10 = base[y1 * WM_ + x];
    float v11 = base[y1 * WM_ + x1];
    QuadH q;
    q.r0 = h2{(_Float16)v00, (_Float16)v01};
    q.r1 = h2{(_Float16)v10, (_Float16)v11};
    quad[t] = q;
}

// ---------------------------------------------------------------------------
// Main cost-volume kernel. One thread = one pixel x DG_(=4) consecutive
// depths. Round-5 load pattern (2 coalesced 8B quad loads / frame-channel);
// cur's 64 channels live in registers (fully-unrolled channel loop -> static
// indices); consecutive depths' quad windows overlap -> L1 temporal hits.
// ---------------------------------------------------------------------------
__global__ __launch_bounds__(256, 4) void cost_volume(
    const float* __restrict__ cur,     // [B][C][HW]
    const QuadH* __restrict__ quad,    // [B*F][C][HW]
    const float* __restrict__ invK,    // [B][16]
    const float* __restrict__ P,       // [B*F][12]
    const float* __restrict__ validF,  // [B*F]
    float* __restrict__ cvOut)         // [B][D][HW]
{
    int blk  = blockIdx.x;             // 1440 = 30 tiles * (B*NDG)
    int tile = blk / (B_ * NDG_);
    int r    = blk % (B_ * NDG_);
    int b    = r / NDG_;
    int dg   = r % NDG_;
    int hw   = tile * 256 + threadIdx.x;

    int x = hw % WM_, y = hw / WM_;
    float fx = (float)x, fy = (float)y;

    const float* ik = invK + (size_t)b * 16;
    float rx = ik[0] * fx + ik[1] * fy + ik[2];
    float ry = ik[4] * fx + ik[5] * fy + ik[6];
    float rz = ik[8] * fx + ik[9] * fy + ik[10];

    bool inter = (x >= 2 && x <= WM_ - 3 && y >= 2 && y <= HM_ - 3);

    float P0[12], P1[12];
    #pragma unroll
    for (int j = 0; j < 12; ++j) P0[j] = P[(b * F_ + 0) * 12 + j];
    #pragma unroll
    for (int j = 0; j < 12; ++j) P1[j] = P[(b * F_ + 1) * 12 + j];
    float pr00 = P0[0]*rx + P0[1]*ry + P0[2]*rz;
    float pr01 = P0[4]*rx + P0[5]*ry + P0[6]*rz;
    float pr02 = P0[8]*rx + P0[9]*ry + P0[10]*rz;
    float pr10 = P1[0]*rx + P1[1]*ry + P1[2]*rz;
    float pr11 = P1[4]*rx + P1[5]*ry + P1[6]*rz;
    float pr12 = P1[8]*rx + P1[9]*ry + P1[10]*rz;
    float vf0 = validF[b * F_ + 0], vf1 = validF[b * F_ + 1];

    // cur channels -> registers (static indices only)
    float curv[C_];
    const float* cp = cur + (size_t)(b * C_ * HW_ + hw);
    #pragma unroll
    for (int c = 0; c < C_; ++c) curv[c] = cp[(size_t)c * HW_];

    const char* qb = (const char*)quad;
    unsigned fb0 = (unsigned)((b * F_ + 0) * C_ * HW_);
    unsigned fb1 = (unsigned)((b * F_ + 1) * C_ * HW_);

    #pragma unroll 1
    for (int i = 0; i < DG_; ++i) {
        int d = dg * DG_ + i;
        float depth = 0.1f + (float)d * (19.9f / 95.0f);

        // frame 0 projection
        float cp00 = fmaf(depth, pr00, P0[3]);
        float cp01 = fmaf(depth, pr01, P0[7]);
        float cp02 = fmaf(depth, pr02, P0[11]);
        float z0 = cp02 + EPS_;
        float gx0 = cp00 / z0, gy0 = cp01 / z0;
        float x0f0 = floorf(gx0), y0f0 = floorf(gy0);
        float wx1_0 = gx0 - x0f0, wy1_0 = gy0 - y0f0;
        float wx0_0 = 1.f - wx1_0, wy0_0 = 1.f - wy1_0;
        int cx0 = min(max((int)x0f0, 0), WM_ - 1);
        int cy0 = min(max((int)y0f0, 0), HM_ - 1);
        h2 wA0 = h2{(_Float16)(wx0_0 * wy0_0), (_Float16)(wx1_0 * wy0_0)};
        h2 wB0 = h2{(_Float16)(wx0_0 * wy1_0), (_Float16)(wx1_0 * wy1_0)};
        bool e0 = (gx0 >= 2.f) && (gx0 <= (float)(WM_ - 2)) &&
                  (gy0 >= 2.f) && (gy0 <= (float)(HM_ - 2)) && inter;
        float ff0 = (e0 ? 1.f : 0.f) * vf0;

        // frame 1 projection
        float cp10 = fmaf(depth, pr10, P1[3]);
        float cp11 = fmaf(depth, pr11, P1[7]);
        float cp12 = fmaf(depth, pr12, P1[11]);
        float z1 = cp12 + EPS_;
        float gx1 = cp10 / z1, gy1 = cp11 / z1;
        float x0f1 = floorf(gx1), y0f1 = floorf(gy1);
        float wx1_1 = gx1 - x0f1, wy1_1 = gy1 - y0f1;
        float wx0_1 = 1.f - wx1_1, wy0_1 = 1.f - wy1_1;
        int cx1 = min(max((int)x0f1, 0), WM_ - 1);
        int cy1 = min(max((int)y0f1, 0), HM_ - 1);
        h2 wA1 = h2{(_Float16)(wx0_1 * wy0_1), (_Float16)(wx1_1 * wy0_1)};
        h2 wB1 = h2{(_Float16)(wx0_1 * wy1_1), (_Float16)(wx1_1 * wy1_1)};
        bool e1 = (gx1 >= 2.f) && (gx1 <= (float)(WM_ - 2)) &&
                  (gy1 >= 2.f) && (gy1 <= (float)(HM_ - 2)) && inter;
        float ff1 = (e1 ? 1.f : 0.f) * vf1;

        size_t oidx = ((size_t)(b * D_ + d)) * HW_ + hw;

        if (__ballot(ff0 > 0.f || ff1 > 0.f) == 0ull) {
            cvOut[oidx] = 0.f;
            continue;
        }

        unsigned oq0 = (fb0 + (unsigned)(cy0 * WM_ + cx0)) * 8u;
        unsigned oq1 = (fb1 + (unsigned)(cy1 * WM_ + cx1)) * 8u;

        float s0 = 0.f, s1 = 0.f;
        #pragma unroll
        for (int c = 0; c < C_; ++c) {
            QuadH q0 = *(const QuadH*)(qb + oq0); oq0 += HW_ * 8u;
            QuadH q1 = *(const QuadH*)(qb + oq1); oq1 += HW_ * 8u;
            float nc = -curv[c];
            s0 += fabsf(FDOT2(q0.r0, wA0, FDOT2(q0.r1, wB0, nc)));
            s1 += fabsf(FDOT2(q1.r0, wA1, FDOT2(q1.r1, wB1, nc)));
        }

        float m0 = s0 * (1.0f / 64.0f) * ff0;
        float m1 = s1 * (1.0f / 64.0f) * ff1;
        float costsum = m0 + m1;
        float counts  = ((m0 > 0.f) ? 1.f : 0.f) + ((m1 > 0.f) ? 1.f : 0.f);
        float scale = (counts > 1.5f) ? (1.0f / (2.0f + EPS_)) : (1.0f / (1.0f + EPS_));
        cvOut[oidx] = costsum * scale;
    }
}

// ---------------------------------------------------------------------------
// Finalize: per (b,hw), max over D, then write cost / missing.
// ---------------------------------------------------------------------------
__global__ __launch_bounds__(256) void finalize(
    const float* __restrict__ cv,   // [B][D][HW]
    float* __restrict__ cost,       // [B][D][HW]
    float* __restrict__ missing)    // [B][D][HW]
{
    int t = blockIdx.x * blockDim.x + threadIdx.x;
    if (t >= B_ * HW_) return;
    int b = t / HW_, hw = t % HW_;
    const float* src = cv + (size_t)b * D_ * HW_ + hw;

    float mx = 0.f;   // all values >= 0
    for (int d = 0; d < D_; ++d)
        mx = fmaxf(mx, src[(size_t)d * HW_]);

    for (int d = 0; d < D_; ++d) {
        float v = src[(size_t)d * HW_];
        float m = (v == 0.f) ? 1.f : 0.f;
        size_t o = (size_t)b * D_ * HW_ + (size_t)d * HW_ + hw;
        cost[o]    = (m != 0.f) ? mx : v;
        missing[o] = m;
    }
}

// ---------------------------------------------------------------------------
extern "C" void kernel_launch(void* const* d_in, const int* in_sizes, int n_in,
                              void* d_out, int out_size, void* d_ws, size_t ws_size,
                              hipStream_t stream)
{
    const float* current = (const float*)d_in[0];  // [B,C,H,W]
    const float* lookup  = (const float*)d_in[1];  // [B,F,C,H,W]
    const float* poses   = (const float*)d_in[2];  // [B,F,4,4]
    const float* K       = (const float*)d_in[3];  // [B,4,4]
    const float* invK    = (const float*)d_in[4];  // [B,4,4]

    float* out = (float*)d_out;
    float* costOut    = out;                 // [B,D,H,W]
    float* missingOut = out + NTOT;          // [B,D,H,W]
    float* cvOut      = out + 2 * NTOT;      // [B,D,H,W] (pre-fill cost)

    // workspace layout: small params first, then the 15.75 MB quad buffer
    float* ws     = (float*)d_ws;
    float* Pmat   = ws;                      // B*F*12 = 48 floats
    float* validF = Pmat + B_ * F_ * 12;     // B*F    = 4 floats
    QuadH* quad   = (QuadH*)(ws + 64);       // B*F*C*HW QuadH = 15,728,640 B

    const int nquad = B_ * F_ * C_ * HW_;        // 1,966,080 = 7680 * 256
    hipLaunchKernelGGL(pack_and_setup, dim3(nquad / 256), dim3(256), 0, stream,
                       lookup, quad, poses, K, Pmat, validF);

    const int nblocks = (HW_ / 256) * B_ * NDG_; // 30 * 48 = 1440
    hipLaunchKernelGGL(cost_volume, dim3(nblocks), dim3(256), 0, stream,
                       current, quad, invK, Pmat, validF, cvOut);

    const int npix = B_ * HW_;                   // 15,360
    hipLaunchKernelGGL(finalize, dim3((npix + 255) / 256), dim3(256), 0, stream,
                       cvOut, costOut, missingOut);
}

// Round 8
// 122.720 us; speedup vs baseline: 1.7405x; 1.5011x over previous
//
#include <hip/hip_runtime.h>
#include <hip/hip_bf16.h>
#include <stdint.h>

// Problem constants (from reference)
#define B_  2
#define F_  2
#define C_  64
#define D_  96
#define HM_ 48
#define WM_ 160
#define HW_ (HM_ * WM_)                 // 7680
#define NTOT ((size_t)B_ * D_ * HW_)    // 1,474,560 per output tensor
#define EPS_ 1e-7f
#define DW_  4                          // depths per block (one per wave)
#define NDG_ (D_ / DW_)                 // 24 depth groups

typedef _Float16 h2 __attribute__((ext_vector_type(2)));
struct QuadH { h2 r0, r1; };            // 8B: (v00,v01),(v10,v11) as f16

#if __has_builtin(__builtin_amdgcn_fdot2)
__device__ __forceinline__ float FDOT2(h2 a, h2 b, float c) {
    return __builtin_amdgcn_fdot2(a, b, c, false);
}
#else
__device__ __forceinline__ float FDOT2(h2 a, h2 b, float c) {
    return (float)a.x * (float)b.x + (float)a.y * (float)b.y + c;
}
#endif

// ---------------------------------------------------------------------------
// Pack corner quads, [n][C][HW] layout (8B per pixel, coalesced).
// Block 0 also computes P = (K@T)[:3] and pose validity.
// ---------------------------------------------------------------------------
__global__ __launch_bounds__(256) void pack_and_setup(
    const float* __restrict__ look,   // [B*F*C][HW]
    QuadH* __restrict__ quad,         // [B*F*C*HW]
    const float* __restrict__ poses,
    const float* __restrict__ K,
    float* __restrict__ Pout,         // [B*F][12]
    float* __restrict__ validOut)     // [B*F]
{
    if (blockIdx.x == 0 && threadIdx.x < 64) {
        int t = threadIdx.x;
        if (t < B_ * F_ * 12) {
            int j  = t & 3;
            int i  = (t >> 2) % 3;
            int bf = t / 12;
            int b  = bf / F_;
            const float* Kb = K + (size_t)b * 16;
            const float* T  = poses + (size_t)bf * 16;
            float s = 0.f;
            #pragma unroll
            for (int k = 0; k < 4; ++k) s += Kb[i * 4 + k] * T[k * 4 + j];
            Pout[bf * 12 + i * 4 + j] = s;
        }
        if (t < B_ * F_) {
            const float* T = poses + (size_t)t * 16;
            float s = 0.f;
            #pragma unroll
            for (int k = 0; k < 16; ++k) s += T[k];
            validOut[t] = (s != 0.0f) ? 1.0f : 0.0f;
        }
    }

    int t = blockIdx.x * 256 + threadIdx.x;   // exact: B*F*C*HW = 7680*256
    int hw = t % HW_;
    int n  = t / HW_;                          // (b*F+f)*C + c
    int x = hw % WM_, y = hw / WM_;
    int x1 = min(x + 1, WM_ - 1), y1 = min(y + 1, HM_ - 1);
    const float* base = look + (size_t)n * HW_;
    float v00 = base[y  * WM_ + x];
    float v01 = base[y  * WM_ + x1];
    float v10 = base[y1 * WM_ + x];
    float v11 = base[y1 * WM_ + x1];
    QuadH q;
    q.r0 = h2{(_Float16)v00, (_Float16)v01};
    q.r1 = h2{(_Float16)v10, (_Float16)v11};
    quad[t] = q;
}

// ---------------------------------------------------------------------------
// Main cost-volume kernel. One thread per output (b,d,hw) -- identical
// per-thread structure to the proven round-5 kernel. Block mapping changed:
// the block's 4 waves cover 4 CONSECUTIVE DEPTHS of the SAME 64-pixel
// segment (r5: 4 pixel segments at one depth). The 4 waves run on the CU's
// 4 SIMDs concurrently and sweep channels in near-lockstep; adjacent-depth
// quad windows overlap -> the same L1 lines serve all 4 waves while
// resident, and cur lines are shared exactly 4x. ~2x less L2 traffic with
// zero change to the instruction stream / coalescing / VGPR.
// ---------------------------------------------------------------------------
__global__ __launch_bounds__(256) void cost_volume(
    const float* __restrict__ cur,     // [B][C][HW]
    const QuadH* __restrict__ quad,    // [B*F][C][HW]
    const float* __restrict__ invK,    // [B][16]
    const float* __restrict__ P,       // [B*F][12]
    const float* __restrict__ validF,  // [B*F]
    float* __restrict__ cvOut)         // [B][D][HW]
{
    int blk  = blockIdx.x;             // 5760 = 120 tile64 * (B_*NDG_)
    int tile = blk / (B_ * NDG_);
    int r    = blk % (B_ * NDG_);
    int b    = r / NDG_;
    int dg   = r % NDG_;
    int wave = threadIdx.x >> 6;
    int lane = threadIdx.x & 63;
    int d    = dg * DW_ + wave;
    int hw   = tile * 64 + lane;

    int x = hw % WM_, y = hw / WM_;
    float fx = (float)x, fy = (float)y;

    const float* ik = invK + (size_t)b * 16;
    float rx = ik[0] * fx + ik[1] * fy + ik[2];
    float ry = ik[4] * fx + ik[5] * fy + ik[6];
    float rz = ik[8] * fx + ik[9] * fy + ik[10];

    float depth = 0.1f + (float)d * (19.9f / 95.0f);
    float qx = depth * rx, qy = depth * ry, qz = depth * rz;

    bool inter = (x >= 2 && x <= WM_ - 3 && y >= 2 && y <= HM_ - 3);

    unsigned oq[F_];                 // byte offsets into quad[]
    h2 w01[F_], w23[F_];             // packed f16 bilinear weights
    float ff[F_];

    #pragma unroll
    for (int f = 0; f < F_; ++f) {
        const float* Pf = P + (size_t)(b * F_ + f) * 12;
        float cp0 = Pf[0] * qx + Pf[1] * qy + Pf[2]  * qz + Pf[3];
        float cp1 = Pf[4] * qx + Pf[5] * qy + Pf[6]  * qz + Pf[7];
        float cp2 = Pf[8] * qx + Pf[9] * qy + Pf[10] * qz + Pf[11];
        float z  = cp2 + EPS_;
        float gx = cp0 / z, gy = cp1 / z;

        float x0f = floorf(gx), y0f = floorf(gy);
        float wx1 = gx - x0f, wy1 = gy - y0f;
        float wx0 = 1.f - wx1, wy0 = 1.f - wy1;

        int x0 = (int)x0f, y0 = (int)y0f;
        int cx = min(max(x0, 0), WM_ - 1);
        int cy = min(max(y0, 0), HM_ - 1);

        oq[f] = ((unsigned)((b * F_ + f) * C_ * HW_) +
                 (unsigned)(cy * WM_ + cx)) * 8u;

        w01[f] = h2{(_Float16)(wx0 * wy0), (_Float16)(wx1 * wy0)};
        w23[f] = h2{(_Float16)(wx0 * wy1), (_Float16)(wx1 * wy1)};

        bool e = (gx >= 2.f) && (gx <= (float)(WM_ - 2)) &&
                 (gy >= 2.f) && (gy <= (float)(HM_ - 2)) && inter;
        ff[f] = (e ? 1.f : 0.f) * validF[b * F_ + f];
    }

    size_t oidx = ((size_t)(b * D_ + d)) * HW_ + hw;

    // Wave-uniform early-out
    if (__ballot(ff[0] > 0.f || ff[1] > 0.f) == 0ull) {
        cvOut[oidx] = 0.f;
        return;
    }

    const char* qb = (const char*)quad;
    const char* cb = (const char*)cur;
    unsigned oq0 = oq[0], oq1 = oq[1];
    unsigned oc  = (unsigned)(b * C_ * HW_ + hw) * 4u;

    h2 w01_0 = w01[0], w23_0 = w23[0];
    h2 w01_1 = w01[1], w23_1 = w23[1];

    float s0 = 0.f, s1 = 0.f;
    #pragma unroll 8
    for (int c = 0; c < C_; ++c) {
        QuadH q0 = *(const QuadH*)(qb + oq0); oq0 += HW_ * 8u;
        QuadH q1 = *(const QuadH*)(qb + oq1); oq1 += HW_ * 8u;
        float cvv = *(const float*)(cb + oc); oc += HW_ * 4u;
        float ncvv = -cvv;

        float a0 = FDOT2(q0.r0, w01_0, FDOT2(q0.r1, w23_0, ncvv));
        float a1 = FDOT2(q1.r0, w01_1, FDOT2(q1.r1, w23_1, ncvv));
        s0 += fabsf(a0);
        s1 += fabsf(a1);
    }

    float m0 = s0 * (1.0f / 64.0f) * ff[0];
    float m1 = s1 * (1.0f / 64.0f) * ff[1];
    float costsum = m0 + m1;
    float counts  = ((m0 > 0.f) ? 1.f : 0.f) + ((m1 > 0.f) ? 1.f : 0.f);
    float scale = (counts > 1.5f) ? (1.0f / (2.0f + EPS_)) : (1.0f / (1.0f + EPS_));
    cvOut[oidx] = costsum * scale;
}

// ---------------------------------------------------------------------------
// Finalize: per (b,hw), max over D, then write cost / missing.
// ---------------------------------------------------------------------------
__global__ __launch_bounds__(256) void finalize(
    const float* __restrict__ cv,   // [B][D][HW]
    float* __restrict__ cost,       // [B][D][HW]
    float* __restrict__ missing)    // [B][D][HW]
{
    int t = blockIdx.x * blockDim.x + threadIdx.x;
    if (t >= B_ * HW_) return;
    int b = t / HW_, hw = t % HW_;
    const float* src = cv + (size_t)b * D_ * HW_ + hw;

    float mx = 0.f;   // all values >= 0
    for (int d = 0; d < D_; ++d)
        mx = fmaxf(mx, src[(size_t)d * HW_]);

    for (int d = 0; d < D_; ++d) {
        float v = src[(size_t)d * HW_];
        float m = (v == 0.f) ? 1.f : 0.f;
        size_t o = (size_t)b * D_ * HW_ + (size_t)d * HW_ + hw;
        cost[o]    = (m != 0.f) ? mx : v;
        missing[o] = m;
    }
}

// ---------------------------------------------------------------------------
extern "C" void kernel_launch(void* const* d_in, const int* in_sizes, int n_in,
                              void* d_out, int out_size, void* d_ws, size_t ws_size,
                              hipStream_t stream)
{
    const float* current = (const float*)d_in[0];  // [B,C,H,W]
    const float* lookup  = (const float*)d_in[1];  // [B,F,C,H,W]
    const float* poses   = (const float*)d_in[2];  // [B,F,4,4]
    const float* K       = (const float*)d_in[3];  // [B,4,4]
    const float* invK    = (const float*)d_in[4];  // [B,4,4]

    float* out = (float*)d_out;
    float* costOut    = out;                 // [B,D,H,W]
    float* missingOut = out + NTOT;          // [B,D,H,W]
    float* cvOut      = out + 2 * NTOT;      // [B,D,H,W] (pre-fill cost)

    // workspace layout: small params first, then the 15.75 MB quad buffer
    float* ws     = (float*)d_ws;
    float* Pmat   = ws;                      // B*F*12 = 48 floats
    float* validF = Pmat + B_ * F_ * 12;     // B*F    = 4 floats
    QuadH* quad   = (QuadH*)(ws + 64);       // B*F*C*HW QuadH = 15,728,640 B

    const int nquad = B_ * F_ * C_ * HW_;        // 1,966,080 = 7680 * 256
    hipLaunchKernelGGL(pack_and_setup, dim3(nquad / 256), dim3(256), 0, stream,
                       lookup, quad, poses, K, Pmat, validF);

    const int nblocks = (HW_ / 64) * B_ * NDG_;  // 120 * 48 = 5760
    hipLaunchKernelGGL(cost_volume, dim3(nblocks), dim3(256), 0, stream,
                       current, quad, invK, Pmat, validF, cvOut);

    const int npix = B_ * HW_;                   // 15,360
    hipLaunchKernelGGL(finalize, dim3((npix + 255) / 256), dim3(256), 0, stream,
                       cvOut, costOut, missingOut);
}

// Round 9
// 91.076 us; speedup vs baseline: 2.3452x; 1.3475x over previous
//
#include <hip/hip_runtime.h>
#include <hip/hip_bf16.h>
#include <stdint.h>

// Problem constants (from reference)
#define B_  2
#define F_  2
#define C_  64
#define D_  96
#define HM_ 48
#define WM_ 160
#define HW_ (HM_ * WM_)                 // 7680
#define NTOT ((size_t)B_ * D_ * HW_)    // 1,474,560 per output tensor
#define EPS_ 1e-7f
#define DW_  4                          // depths per block (one per wave)
#define NDG_ (D_ / DW_)                 // 24 depth groups

typedef _Float16 h2 __attribute__((ext_vector_type(2)));
struct QuadH { h2 r0, r1; };            // 8B: (v00,v01),(v10,v11) as f16
struct Quad2 { QuadH a, b; };           // 16B: quads of channels 2cp, 2cp+1
struct H4    { h2 a, b; };              // 8B: 4 f16 cur channels

#if __has_builtin(__builtin_amdgcn_fdot2)
__device__ __forceinline__ float FDOT2(h2 a, h2 b, float c) {
    return __builtin_amdgcn_fdot2(a, b, c, false);
}
#else
__device__ __forceinline__ float FDOT2(h2 a, h2 b, float c) {
    return (float)a.x * (float)b.x + (float)a.y * (float)b.y + c;
}
#endif

#define NQBLK ((B_ * F_ * (C_/2) * HW_) / 256)   // 3840
#define NCBLK ((B_ * (C_/4) * HW_) / 256)        // 960

// ---------------------------------------------------------------------------
// Pack:
//  * quad2 [n][C/2][HW] (16B): corner quads of channel pairs (2cp,2cp+1)
//  * cur2  [b][C/4][HW] (8B): 4 f16 cur channels
// Block 0 also computes P = (K@T)[:3] and pose validity.
// ---------------------------------------------------------------------------
__global__ __launch_bounds__(256) void pack_and_setup(
    const float* __restrict__ look,   // [B*F*C][HW]
    const float* __restrict__ cur,    // [B*C][HW]
    Quad2* __restrict__ quad2,
    H4* __restrict__ cur2,
    const float* __restrict__ poses,
    const float* __restrict__ K,
    float* __restrict__ Pout,         // [B*F][12]
    float* __restrict__ validOut)     // [B*F]
{
    if (blockIdx.x == 0 && threadIdx.x < 64) {
        int t = threadIdx.x;
        if (t < B_ * F_ * 12) {
            int j  = t & 3;
            int i  = (t >> 2) % 3;
            int bf = t / 12;
            int b  = bf / F_;
            const float* Kb = K + (size_t)b * 16;
            const float* T  = poses + (size_t)bf * 16;
            float s = 0.f;
            #pragma unroll
            for (int k = 0; k < 4; ++k) s += Kb[i * 4 + k] * T[k * 4 + j];
            Pout[bf * 12 + i * 4 + j] = s;
        }
        if (t < B_ * F_) {
            const float* T = poses + (size_t)t * 16;
            float s = 0.f;
            #pragma unroll
            for (int k = 0; k < 16; ++k) s += T[k];
            validOut[t] = (s != 0.0f) ? 1.0f : 0.0f;
        }
    }

    int blk = blockIdx.x;
    if (blk < NQBLK) {
        int t   = blk * 256 + threadIdx.x;     // B*F*(C/2)*HW
        int pix = t % HW_;
        int rem = t / HW_;
        int cp  = rem % (C_ / 2);
        int n   = rem / (C_ / 2);
        int x = pix % WM_, y = pix / WM_;
        int x1 = min(x + 1, WM_ - 1), y1 = min(y + 1, HM_ - 1);
        const float* b0 = look + ((size_t)n * C_ + 2 * cp) * HW_;
        const float* b1 = b0 + HW_;
        Quad2 q;
        q.a.r0 = h2{(_Float16)b0[y  * WM_ + x], (_Float16)b0[y  * WM_ + x1]};
        q.a.r1 = h2{(_Float16)b0[y1 * WM_ + x], (_Float16)b0[y1 * WM_ + x1]};
        q.b.r0 = h2{(_Float16)b1[y  * WM_ + x], (_Float16)b1[y  * WM_ + x1]};
        q.b.r1 = h2{(_Float16)b1[y1 * WM_ + x], (_Float16)b1[y1 * WM_ + x1]};
        quad2[t] = q;
    } else {
        int t   = (blk - NQBLK) * 256 + threadIdx.x;   // B*(C/4)*HW
        int pix = t % HW_;
        int rem = t / HW_;
        int c4  = rem % (C_ / 4);
        int b   = rem / (C_ / 4);
        const float* p = cur + ((size_t)b * C_ + 4 * c4) * HW_ + pix;
        H4 h;
        h.a = h2{(_Float16)p[0],             (_Float16)p[(size_t)HW_]};
        h.b = h2{(_Float16)p[2 * (size_t)HW_], (_Float16)p[3 * (size_t)HW_]};
        cur2[t] = h;
    }
}

// ---------------------------------------------------------------------------
// Main cost-volume kernel. One thread per output (b,d,hw). Block's 4 waves =
// 4 consecutive depths of the same 64-pixel segment (r8 mapping, keeps L1/L2
// sharing). Inner loop processes 4 channels per iteration with only 5 load
// instructions (4x 16B quad-pair + 1x 8B cur-quad) -- 80 loads/thread total
// vs 192 in r8, attacking the vector-memory address-throughput limit.
// ---------------------------------------------------------------------------
__global__ __launch_bounds__(256) void cost_volume(
    const float* __restrict__ cur_unused,  // kept for signature clarity
    const Quad2* __restrict__ quad2,   // [B*F][C/2][HW]
    const H4* __restrict__ cur2,       // [B][C/4][HW]
    const float* __restrict__ invK,    // [B][16]
    const float* __restrict__ P,       // [B*F][12]
    const float* __restrict__ validF,  // [B*F]
    float* __restrict__ cvOut)         // [B][D][HW]
{
    int blk  = blockIdx.x;             // 5760 = 120 tile64 * (B_*NDG_)
    int tile = blk / (B_ * NDG_);
    int r    = blk % (B_ * NDG_);
    int b    = r / NDG_;
    int dg   = r % NDG_;
    int wave = threadIdx.x >> 6;
    int lane = threadIdx.x & 63;
    int d    = dg * DW_ + wave;
    int hw   = tile * 64 + lane;

    int x = hw % WM_, y = hw / WM_;
    float fx = (float)x, fy = (float)y;

    const float* ik = invK + (size_t)b * 16;
    float rx = ik[0] * fx + ik[1] * fy + ik[2];
    float ry = ik[4] * fx + ik[5] * fy + ik[6];
    float rz = ik[8] * fx + ik[9] * fy + ik[10];

    float depth = 0.1f + (float)d * (19.9f / 95.0f);
    float qx = depth * rx, qy = depth * ry, qz = depth * rz;

    bool inter = (x >= 2 && x <= WM_ - 3 && y >= 2 && y <= HM_ - 3);

    unsigned pixc[F_];
    h2 w01[F_], w23[F_];
    float ff[F_];

    #pragma unroll
    for (int f = 0; f < F_; ++f) {
        const float* Pf = P + (size_t)(b * F_ + f) * 12;
        float cp0 = Pf[0] * qx + Pf[1] * qy + Pf[2]  * qz + Pf[3];
        float cp1 = Pf[4] * qx + Pf[5] * qy + Pf[6]  * qz + Pf[7];
        float cp2 = Pf[8] * qx + Pf[9] * qy + Pf[10] * qz + Pf[11];
        float z  = cp2 + EPS_;
        float gx = cp0 / z, gy = cp1 / z;

        float x0f = floorf(gx), y0f = floorf(gy);
        float wx1 = gx - x0f, wy1 = gy - y0f;
        float wx0 = 1.f - wx1, wy0 = 1.f - wy1;

        int x0 = (int)x0f, y0 = (int)y0f;
        int cx = min(max(x0, 0), WM_ - 1);
        int cy = min(max(y0, 0), HM_ - 1);
        pixc[f] = (unsigned)(cy * WM_ + cx);

        w01[f] = h2{(_Float16)(wx0 * wy0), (_Float16)(wx1 * wy0)};
        w23[f] = h2{(_Float16)(wx0 * wy1), (_Float16)(wx1 * wy1)};

        bool e = (gx >= 2.f) && (gx <= (float)(WM_ - 2)) &&
                 (gy >= 2.f) && (gy <= (float)(HM_ - 2)) && inter;
        ff[f] = (e ? 1.f : 0.f) * validF[b * F_ + f];
    }

    size_t oidx = ((size_t)(b * D_ + d)) * HW_ + hw;

    // Wave-uniform early-out
    if (__ballot(ff[0] > 0.f || ff[1] > 0.f) == 0ull) {
        cvOut[oidx] = 0.f;
        return;
    }

    const char* qbp = (const char*)quad2;
    const char* cbp = (const char*)cur2;
    unsigned oA = ((unsigned)((b * F_ + 0) * (C_ / 2)) * HW_ + pixc[0]) * 16u;
    unsigned oB = ((unsigned)((b * F_ + 1) * (C_ / 2)) * HW_ + pixc[1]) * 16u;
    unsigned oc = ((unsigned)(b * (C_ / 4)) * HW_ + (unsigned)hw) * 8u;

    h2 wA0 = w01[0], wB0 = w23[0];
    h2 wA1 = w01[1], wB1 = w23[1];

    float s0 = 0.f, s1 = 0.f;
    #pragma unroll 4
    for (int c4 = 0; c4 < C_ / 4; ++c4) {
        Quad2 qa0 = *(const Quad2*)(qbp + oA);
        Quad2 qa1 = *(const Quad2*)(qbp + oA + (unsigned)HW_ * 16u);
        oA += (unsigned)HW_ * 32u;
        Quad2 qb0 = *(const Quad2*)(qbp + oB);
        Quad2 qb1 = *(const Quad2*)(qbp + oB + (unsigned)HW_ * 16u);
        oB += (unsigned)HW_ * 32u;
        H4 cu = *(const H4*)(cbp + oc); oc += (unsigned)HW_ * 8u;

        float c0 = -(float)cu.a.x, c1 = -(float)cu.a.y;
        float c2 = -(float)cu.b.x, c3 = -(float)cu.b.y;

        s0 += fabsf(FDOT2(qa0.a.r0, wA0, FDOT2(qa0.a.r1, wB0, c0)));
        s1 += fabsf(FDOT2(qb0.a.r0, wA1, FDOT2(qb0.a.r1, wB1, c0)));
        s0 += fabsf(FDOT2(qa0.b.r0, wA0, FDOT2(qa0.b.r1, wB0, c1)));
        s1 += fabsf(FDOT2(qb0.b.r0, wA1, FDOT2(qb0.b.r1, wB1, c1)));
        s0 += fabsf(FDOT2(qa1.a.r0, wA0, FDOT2(qa1.a.r1, wB0, c2)));
        s1 += fabsf(FDOT2(qb1.a.r0, wA1, FDOT2(qb1.a.r1, wB1, c2)));
        s0 += fabsf(FDOT2(qa1.b.r0, wA0, FDOT2(qa1.b.r1, wB0, c3)));
        s1 += fabsf(FDOT2(qb1.b.r0, wA1, FDOT2(qb1.b.r1, wB1, c3)));
    }

    float m0 = s0 * (1.0f / 64.0f) * ff[0];
    float m1 = s1 * (1.0f / 64.0f) * ff[1];
    float costsum = m0 + m1;
    float counts  = ((m0 > 0.f) ? 1.f : 0.f) + ((m1 > 0.f) ? 1.f : 0.f);
    float scale = (counts > 1.5f) ? (1.0f / (2.0f + EPS_)) : (1.0f / (1.0f + EPS_));
    cvOut[oidx] = costsum * scale;
}

// ---------------------------------------------------------------------------
// Finalize: per (b,hw), max over D, then write cost / missing.
// (Also overwrites the cur2 stash that lived in the costOut region.)
// ---------------------------------------------------------------------------
__global__ __launch_bounds__(256) void finalize(
    const float* __restrict__ cv,   // [B][D][HW]
    float* __restrict__ cost,       // [B][D][HW]
    float* __restrict__ missing)    // [B][D][HW]
{
    int t = blockIdx.x * blockDim.x + threadIdx.x;
    if (t >= B_ * HW_) return;
    int b = t / HW_, hw = t % HW_;
    const float* src = cv + (size_t)b * D_ * HW_ + hw;

    float mx = 0.f;   // all values >= 0
    for (int d = 0; d < D_; ++d)
        mx = fmaxf(mx, src[(size_t)d * HW_]);

    for (int d = 0; d < D_; ++d) {
        float v = src[(size_t)d * HW_];
        float m = (v == 0.f) ? 1.f : 0.f;
        size_t o = (size_t)b * D_ * HW_ + (size_t)d * HW_ + hw;
        cost[o]    = (m != 0.f) ? mx : v;
        missing[o] = m;
    }
}

// ---------------------------------------------------------------------------
extern "C" void kernel_launch(void* const* d_in, const int* in_sizes, int n_in,
                              void* d_out, int out_size, void* d_ws, size_t ws_size,
                              hipStream_t stream)
{
    const float* current = (const float*)d_in[0];  // [B,C,H,W]
    const float* lookup  = (const float*)d_in[1];  // [B,F,C,H,W]
    const float* poses   = (const float*)d_in[2];  // [B,F,4,4]
    const float* K       = (const float*)d_in[3];  // [B,4,4]
    const float* invK    = (const float*)d_in[4];  // [B,4,4]

    float* out = (float*)d_out;
    float* costOut    = out;                 // [B,D,H,W]
    float* missingOut = out + NTOT;          // [B,D,H,W]
    float* cvOut      = out + 2 * NTOT;      // [B,D,H,W] (pre-fill cost)

    // workspace: params + 15.75 MB quad2 (same footprint as proven rounds)
    float* ws     = (float*)d_ws;
    float* Pmat   = ws;                      // B*F*12 = 48 floats
    float* validF = Pmat + B_ * F_ * 12;     // B*F    = 4 floats
    Quad2* quad2  = (Quad2*)(ws + 64);       // B*F*(C/2)*HW * 16B = 15,728,640 B

    // cur2 stash lives in the costOut region (1.97 MB << 5.9 MB); it is
    // consumed by cost_volume and then overwritten by finalize.
    H4* cur2 = (H4*)costOut;

    const int npack = NQBLK + NCBLK;             // 3840 + 960 = 4800
    hipLaunchKernelGGL(pack_and_setup, dim3(npack), dim3(256), 0, stream,
                       lookup, current, quad2, cur2, poses, K, Pmat, validF);

    const int nblocks = (HW_ / 64) * B_ * NDG_;  // 120 * 48 = 5760
    hipLaunchKernelGGL(cost_volume, dim3(nblocks), dim3(256), 0, stream,
                       current, quad2, cur2, invK, Pmat, validF, cvOut);

    const int npix = B_ * HW_;                   // 15,360
    hipLaunchKernelGGL(finalize, dim3((npix + 255) / 256), dim3(256), 0, stream,
                       cvOut, costOut, missingOut);
}

// Round 10
// 91.043 us; speedup vs baseline: 2.3460x; 1.0004x over previous
//
#include <hip/hip_runtime.h>
#include <hip/hip_bf16.h>
#include <stdint.h>

// Problem constants (from reference)
#define B_  2
#define F_  2
#define C_  64
#define D_  96
#define HM_ 48
#define WM_ 160
#define HW_ (HM_ * WM_)                 // 7680
#define NTOT ((size_t)B_ * D_ * HW_)    // 1,474,560 per output tensor
#define EPS_ 1e-7f
#define DW_  4                          // depths per block (one per wave)
#define NDG_ (D_ / DW_)                 // 24 depth groups

typedef _Float16 half_t;
typedef _Float16 h2 __attribute__((ext_vector_type(2)));
typedef unsigned int u32;

// 16B, corner-major for a channel PAIR (c0,c1):
//   p00=(v00_c0,v00_c1)  p01=(v01_c0,v01_c1)  p10=(v10..)  p11=(v11..)
struct Quad2 { h2 p00, p01, p10, p11; };
// 8B: NEGATED cur, 4 channels as 2 pairs
struct H4    { h2 a, b; };

#if __has_builtin(__builtin_amdgcn_fdot2)
__device__ __forceinline__ float FDOT2(h2 a, h2 b, float c) {
    return __builtin_amdgcn_fdot2(a, b, c, false);
}
#else
__device__ __forceinline__ float FDOT2(h2 a, h2 b, float c) {
    return (float)a.x * (float)b.x + (float)a.y * (float)b.y + c;
}
#endif

__device__ __forceinline__ h2 pabs(h2 v) {
    u32 u; __builtin_memcpy(&u, &v, 4);
    u &= 0x7FFF7FFFu;
    h2 r; __builtin_memcpy(&r, &u, 4);
    return r;
}

#define NQBLK ((B_ * F_ * (C_/2) * HW_) / 256)   // 3840
#define NCBLK ((B_ * (C_/4) * HW_) / 256)        // 960

// ---------------------------------------------------------------------------
// Pack:
//  * quad2 [n][C/2][HW] (16B): corner-major channel-pair quads
//  * cur2  [b][C/4][HW] (8B): 4 NEGATED f16 cur channels
// Block 0 also computes P = (K@T)[:3] and pose validity.
// ---------------------------------------------------------------------------
__global__ __launch_bounds__(256) void pack_and_setup(
    const float* __restrict__ look,   // [B*F*C][HW]
    const float* __restrict__ cur,    // [B*C][HW]
    Quad2* __restrict__ quad2,
    H4* __restrict__ cur2,
    const float* __restrict__ poses,
    const float* __restrict__ K,
    float* __restrict__ Pout,         // [B*F][12]
    float* __restrict__ validOut)     // [B*F]
{
    if (blockIdx.x == 0 && threadIdx.x < 64) {
        int t = threadIdx.x;
        if (t < B_ * F_ * 12) {
            int j  = t & 3;
            int i  = (t >> 2) % 3;
            int bf = t / 12;
            int b  = bf / F_;
            const float* Kb = K + (size_t)b * 16;
            const float* T  = poses + (size_t)bf * 16;
            float s = 0.f;
            #pragma unroll
            for (int k = 0; k < 4; ++k) s += Kb[i * 4 + k] * T[k * 4 + j];
            Pout[bf * 12 + i * 4 + j] = s;
        }
        if (t < B_ * F_) {
            const float* T = poses + (size_t)t * 16;
            float s = 0.f;
            #pragma unroll
            for (int k = 0; k < 16; ++k) s += T[k];
            validOut[t] = (s != 0.0f) ? 1.0f : 0.0f;
        }
    }

    int blk = blockIdx.x;
    if (blk < NQBLK) {
        int t   = blk * 256 + threadIdx.x;     // B*F*(C/2)*HW
        int pix = t % HW_;
        int rem = t / HW_;
        int cp  = rem % (C_ / 2);
        int n   = rem / (C_ / 2);
        int x = pix % WM_, y = pix / WM_;
        int x1 = min(x + 1, WM_ - 1), y1 = min(y + 1, HM_ - 1);
        const float* b0 = look + ((size_t)n * C_ + 2 * cp) * HW_;
        const float* b1 = b0 + HW_;
        Quad2 q;
        q.p00 = h2{(half_t)b0[y  * WM_ + x ], (half_t)b1[y  * WM_ + x ]};
        q.p01 = h2{(half_t)b0[y  * WM_ + x1], (half_t)b1[y  * WM_ + x1]};
        q.p10 = h2{(half_t)b0[y1 * WM_ + x ], (half_t)b1[y1 * WM_ + x ]};
        q.p11 = h2{(half_t)b0[y1 * WM_ + x1], (half_t)b1[y1 * WM_ + x1]};
        quad2[t] = q;
    } else {
        int t   = (blk - NQBLK) * 256 + threadIdx.x;   // B*(C/4)*HW
        int pix = t % HW_;
        int rem = t / HW_;
        int c4  = rem % (C_ / 4);
        int b   = rem / (C_ / 4);
        const float* p = cur + ((size_t)b * C_ + 4 * c4) * HW_ + pix;
        H4 h;
        h.a = h2{(half_t)(-p[0]),               (half_t)(-p[(size_t)HW_])};
        h.b = h2{(half_t)(-p[2 * (size_t)HW_]), (half_t)(-p[3 * (size_t)HW_])};
        cur2[t] = h;
    }
}

// ---------------------------------------------------------------------------
// Main cost-volume kernel. One thread per output (b,d,hw); block's 4 waves =
// 4 consecutive depths of the same 64-pixel segment (r8 mapping).
// Per 4 channels: 5 loads (4x16B quad-pair + 1x8B negcur) and, per channel
// pair per frame, 4 v_pk_fma_f16 (chained from negcur) + packed abs +
// v_pk_add accumulate. f16 partial sums drained to f32 every 8 channels via
// one FDOT2 with weights (1,1).
// ---------------------------------------------------------------------------
__global__ __launch_bounds__(256) void cost_volume(
    const Quad2* __restrict__ quad2,   // [B*F][C/2][HW]
    const H4* __restrict__ cur2,       // [B][C/4][HW]
    const float* __restrict__ invK,    // [B][16]
    const float* __restrict__ P,       // [B*F][12]
    const float* __restrict__ validF,  // [B*F]
    float* __restrict__ cvOut)         // [B][D][HW]
{
    int blk  = blockIdx.x;             // 5760 = 120 tile64 * (B_*NDG_)
    int tile = blk / (B_ * NDG_);
    int r    = blk % (B_ * NDG_);
    int b    = r / NDG_;
    int dg   = r % NDG_;
    int wave = threadIdx.x >> 6;
    int lane = threadIdx.x & 63;
    int d    = dg * DW_ + wave;
    int hw   = tile * 64 + lane;

    int x = hw % WM_, y = hw / WM_;
    float fx = (float)x, fy = (float)y;

    const float* ik = invK + (size_t)b * 16;
    float rx = ik[0] * fx + ik[1] * fy + ik[2];
    float ry = ik[4] * fx + ik[5] * fy + ik[6];
    float rz = ik[8] * fx + ik[9] * fy + ik[10];

    float depth = 0.1f + (float)d * (19.9f / 95.0f);
    float qx = depth * rx, qy = depth * ry, qz = depth * rz;

    bool inter = (x >= 2 && x <= WM_ - 3 && y >= 2 && y <= HM_ - 3);

    unsigned pixc[F_];
    float wf[F_][4];
    float ff[F_];

    #pragma unroll
    for (int f = 0; f < F_; ++f) {
        const float* Pf = P + (size_t)(b * F_ + f) * 12;
        float cp0 = Pf[0] * qx + Pf[1] * qy + Pf[2]  * qz + Pf[3];
        float cp1 = Pf[4] * qx + Pf[5] * qy + Pf[6]  * qz + Pf[7];
        float cp2 = Pf[8] * qx + Pf[9] * qy + Pf[10] * qz + Pf[11];
        float z  = cp2 + EPS_;
        float gx = cp0 / z, gy = cp1 / z;

        float x0f = floorf(gx), y0f = floorf(gy);
        float wx1 = gx - x0f, wy1 = gy - y0f;
        float wx0 = 1.f - wx1, wy0 = 1.f - wy1;

        int x0 = (int)x0f, y0 = (int)y0f;
        int cx = min(max(x0, 0), WM_ - 1);
        int cy = min(max(y0, 0), HM_ - 1);
        pixc[f] = (unsigned)(cy * WM_ + cx);

        wf[f][0] = wx0 * wy0;
        wf[f][1] = wx1 * wy0;
        wf[f][2] = wx0 * wy1;
        wf[f][3] = wx1 * wy1;

        bool e = (gx >= 2.f) && (gx <= (float)(WM_ - 2)) &&
                 (gy >= 2.f) && (gy <= (float)(HM_ - 2)) && inter;
        ff[f] = (e ? 1.f : 0.f) * validF[b * F_ + f];
    }

    size_t oidx = ((size_t)(b * D_ + d)) * HW_ + hw;

    // Wave-uniform early-out
    if (__ballot(ff[0] > 0.f || ff[1] > 0.f) == 0ull) {
        cvOut[oidx] = 0.f;
        return;
    }

    // packed (duplicated) f16 weights per frame
    h2 W00_0 = h2{(half_t)wf[0][0], (half_t)wf[0][0]};
    h2 W01_0 = h2{(half_t)wf[0][1], (half_t)wf[0][1]};
    h2 W10_0 = h2{(half_t)wf[0][2], (half_t)wf[0][2]};
    h2 W11_0 = h2{(half_t)wf[0][3], (half_t)wf[0][3]};
    h2 W00_1 = h2{(half_t)wf[1][0], (half_t)wf[1][0]};
    h2 W01_1 = h2{(half_t)wf[1][1], (half_t)wf[1][1]};
    h2 W10_1 = h2{(half_t)wf[1][2], (half_t)wf[1][2]};
    h2 W11_1 = h2{(half_t)wf[1][3], (half_t)wf[1][3]};

    const char* qbp = (const char*)quad2;
    const char* cbp = (const char*)cur2;
    unsigned oA = ((u32)((b * F_ + 0) * (C_ / 2)) * HW_ + pixc[0]) * 16u;
    unsigned oB = ((u32)((b * F_ + 1) * (C_ / 2)) * HW_ + pixc[1]) * 16u;
    unsigned oc = ((u32)(b * (C_ / 4)) * HW_ + (u32)hw) * 8u;

    const h2 ones = h2{(half_t)1.f, (half_t)1.f};
    float s0 = 0.f, s1 = 0.f;

    #pragma unroll 2
    for (int g = 0; g < 8; ++g) {          // 8 groups x 8 channels
        h2 sA0 = h2{(half_t)0.f, (half_t)0.f};
        h2 sA1 = h2{(half_t)0.f, (half_t)0.f};
        h2 sB0 = h2{(half_t)0.f, (half_t)0.f};
        h2 sB1 = h2{(half_t)0.f, (half_t)0.f};
        #pragma unroll
        for (int it = 0; it < 2; ++it) {   // 2 x 4 channels
            Quad2 qa0 = *(const Quad2*)(qbp + oA);
            Quad2 qa1 = *(const Quad2*)(qbp + oA + (u32)HW_ * 16u);
            oA += (u32)HW_ * 32u;
            Quad2 qb0 = *(const Quad2*)(qbp + oB);
            Quad2 qb1 = *(const Quad2*)(qbp + oB + (u32)HW_ * 16u);
            oB += (u32)HW_ * 32u;
            H4 cu = *(const H4*)(cbp + oc); oc += (u32)HW_ * 8u;

            h2 aa0 = qa0.p11 * W11_0 + cu.a;
            aa0 = qa0.p10 * W10_0 + aa0;
            aa0 = qa0.p01 * W01_0 + aa0;
            aa0 = qa0.p00 * W00_0 + aa0;
            sA0 += pabs(aa0);

            h2 aa1 = qa1.p11 * W11_0 + cu.b;
            aa1 = qa1.p10 * W10_0 + aa1;
            aa1 = qa1.p01 * W01_0 + aa1;
            aa1 = qa1.p00 * W00_0 + aa1;
            sA1 += pabs(aa1);

            h2 bb0 = qb0.p11 * W11_1 + cu.a;
            bb0 = qb0.p10 * W10_1 + bb0;
            bb0 = qb0.p01 * W01_1 + bb0;
            bb0 = qb0.p00 * W00_1 + bb0;
            sB0 += pabs(bb0);

            h2 bb1 = qb1.p11 * W11_1 + cu.b;
            bb1 = qb1.p10 * W10_1 + bb1;
            bb1 = qb1.p01 * W01_1 + bb1;
            bb1 = qb1.p00 * W00_1 + bb1;
            sB1 += pabs(bb1);
        }
        s0 = FDOT2(sA0, ones, s0);
        s0 = FDOT2(sA1, ones, s0);
        s1 = FDOT2(sB0, ones, s1);
        s1 = FDOT2(sB1, ones, s1);
    }

    float m0 = s0 * (1.0f / 64.0f) * ff[0];
    float m1 = s1 * (1.0f / 64.0f) * ff[1];
    float costsum = m0 + m1;
    float counts  = ((m0 > 0.f) ? 1.f : 0.f) + ((m1 > 0.f) ? 1.f : 0.f);
    float scale = (counts > 1.5f) ? (1.0f / (2.0f + EPS_)) : (1.0f / (1.0f + EPS_));
    cvOut[oidx] = costsum * scale;
}

// ---------------------------------------------------------------------------
// Finalize: per (b,hw), max over D, then write cost / missing.
// (Also overwrites the cur2 stash that lived in the costOut region.)
// ---------------------------------------------------------------------------
__global__ __launch_bounds__(256) void finalize(
    const float* __restrict__ cv,   // [B][D][HW]
    float* __restrict__ cost,       // [B][D][HW]
    float* __restrict__ missing)    // [B][D][HW]
{
    int t = blockIdx.x * blockDim.x + threadIdx.x;
    if (t >= B_ * HW_) return;
    int b = t / HW_, hw = t % HW_;
    const float* src = cv + (size_t)b * D_ * HW_ + hw;

    float mx = 0.f;   // all values >= 0
    for (int d = 0; d < D_; ++d)
        mx = fmaxf(mx, src[(size_t)d * HW_]);

    for (int d = 0; d < D_; ++d) {
        float v = src[(size_t)d * HW_];
        float m = (v == 0.f) ? 1.f : 0.f;
        size_t o = (size_t)b * D_ * HW_ + (size_t)d * HW_ + hw;
        cost[o]    = (m != 0.f) ? mx : v;
        missing[o] = m;
    }
}

// ---------------------------------------------------------------------------
extern "C" void kernel_launch(void* const* d_in, const int* in_sizes, int n_in,
                              void* d_out, int out_size, void* d_ws, size_t ws_size,
                              hipStream_t stream)
{
    const float* current = (const float*)d_in[0];  // [B,C,H,W]
    const float* lookup  = (const float*)d_in[1];  // [B,F,C,H,W]
    const float* poses   = (const float*)d_in[2];  // [B,F,4,4]
    const float* K       = (const float*)d_in[3];  // [B,4,4]
    const float* invK    = (const float*)d_in[4];  // [B,4,4]

    float* out = (float*)d_out;
    float* costOut    = out;                 // [B,D,H,W]
    float* missingOut = out + NTOT;          // [B,D,H,W]
    float* cvOut      = out + 2 * NTOT;      // [B,D,H,W] (pre-fill cost)

    // workspace: params + 15.75 MB quad2 (same footprint as proven rounds)
    float* ws     = (float*)d_ws;
    float* Pmat   = ws;                      // B*F*12 = 48 floats
    float* validF = Pmat + B_ * F_ * 12;     // B*F    = 4 floats
    Quad2* quad2  = (Quad2*)(ws + 64);       // B*F*(C/2)*HW * 16B = 15,728,640 B

    // cur2 stash lives in the costOut region (1.97 MB << 5.9 MB); it is
    // consumed by cost_volume and then overwritten by finalize.
    H4* cur2 = (H4*)costOut;

    const int npack = NQBLK + NCBLK;             // 3840 + 960 = 4800
    hipLaunchKernelGGL(pack_and_setup, dim3(npack), dim3(256), 0, stream,
                       lookup, current, quad2, cur2, poses, K, Pmat, validF);

    const int nblocks = (HW_ / 64) * B_ * NDG_;  // 120 * 48 = 5760
    hipLaunchKernelGGL(cost_volume, dim3(nblocks), dim3(256), 0, stream,
                       quad2, cur2, invK, Pmat, validF, cvOut);

    const int npix = B_ * HW_;                   // 15,360
    hipLaunchKernelGGL(finalize, dim3((npix + 255) / 256), dim3(256), 0, stream,
                       cvOut, costOut, missingOut);
}

// Round 11
// 76.538 us; speedup vs baseline: 2.7907x; 1.1895x over previous
//
#include <hip/hip_runtime.h>
#include <hip/hip_bf16.h>
#include <stdint.h>

#if __has_builtin(__builtin_amdgcn_cvt_pk_f32_fp8) && __has_builtin(__builtin_amdgcn_cvt_pk_fp8_f32)
#define HAS_HW_FP8 1
#else
#define HAS_HW_FP8 0
#include <hip/hip_fp8.h>
#endif

// Problem constants (from reference)
#define B_  2
#define F_  2
#define C_  64
#define D_  96
#define HM_ 48
#define WM_ 160
#define HW_ (HM_ * WM_)                 // 7680
#define NTOT ((size_t)B_ * D_ * HW_)    // 1,474,560 per output tensor
#define EPS_ 1e-7f
#define DW_  4                          // depths per block (one per wave)
#define NDG_ (D_ / DW_)                 // 24 depth groups

typedef _Float16 half_t;
typedef _Float16 h2 __attribute__((ext_vector_type(2)));
typedef float f2 __attribute__((ext_vector_type(2)));
typedef unsigned int u32;

// 8B: NEGATED cur, 4 f16 channels as 2 pairs
struct H4 { h2 a, b; };

// fp8 quad entry (16B): .x=p00, .y=p01, .z=p10, .w=p11; each u32 = 4 channels
// (c0..c3) as e4m3 bytes.

__device__ __forceinline__ u32 pk4_fp8(float a, float b, float c, float d) {
#if HAS_HW_FP8
    int r = __builtin_amdgcn_cvt_pk_fp8_f32(a, b, 0, false);
    r = __builtin_amdgcn_cvt_pk_fp8_f32(c, d, r, true);
    return (u32)r;
#else
    __hip_fp8_e4m3 qa(a), qb(b), qc(c), qd(d);
    return (u32)qa.__x | ((u32)qb.__x << 8) | ((u32)qc.__x << 16) |
           ((u32)qd.__x << 24);
#endif
}

template <bool HI>
__device__ __forceinline__ f2 fp8pk(u32 v) {
#if HAS_HW_FP8
    return __builtin_amdgcn_cvt_pk_f32_fp8((int)v, HI);
#else
    u32 w = HI ? (v >> 16) : v;
    __hip_fp8_e4m3 q0, q1;
    q0.__x = (uint8_t)(w & 0xff);
    q1.__x = (uint8_t)((w >> 8) & 0xff);
    f2 r; r.x = (float)q0; r.y = (float)q1;
    return r;
#endif
}

#define NQBLK ((B_ * F_ * (C_/4) * HW_) / 256)   // 1920
#define NCBLK ((B_ * (C_/4) * HW_) / 256)        // 960

// ---------------------------------------------------------------------------
// Pack:
//  * quad4 [n][C/4][HW] (16B): corner-major fp8 quads, 4 channels per entry
//  * cur2  [b][C/4][HW] (8B): 4 NEGATED f16 cur channels
// Block 0 also computes P = (K@T)[:3] and pose validity.
// ---------------------------------------------------------------------------
__global__ __launch_bounds__(256) void pack_and_setup(
    const float* __restrict__ look,   // [B*F*C][HW]
    const float* __restrict__ cur,    // [B*C][HW]
    uint4* __restrict__ quad4,
    H4* __restrict__ cur2,
    const float* __restrict__ poses,
    const float* __restrict__ K,
    float* __restrict__ Pout,         // [B*F][12]
    float* __restrict__ validOut)     // [B*F]
{
    if (blockIdx.x == 0 && threadIdx.x < 64) {
        int t = threadIdx.x;
        if (t < B_ * F_ * 12) {
            int j  = t & 3;
            int i  = (t >> 2) % 3;
            int bf = t / 12;
            int b  = bf / F_;
            const float* Kb = K + (size_t)b * 16;
            const float* T  = poses + (size_t)bf * 16;
            float s = 0.f;
            #pragma unroll
            for (int k = 0; k < 4; ++k) s += Kb[i * 4 + k] * T[k * 4 + j];
            Pout[bf * 12 + i * 4 + j] = s;
        }
        if (t < B_ * F_) {
            const float* T = poses + (size_t)t * 16;
            float s = 0.f;
            #pragma unroll
            for (int k = 0; k < 16; ++k) s += T[k];
            validOut[t] = (s != 0.0f) ? 1.0f : 0.0f;
        }
    }

    int blk = blockIdx.x;
    if (blk < NQBLK) {
        int t   = blk * 256 + threadIdx.x;     // B*F*(C/4)*HW
        int pix = t % HW_;
        int rem = t / HW_;
        int c4  = rem % (C_ / 4);
        int n   = rem / (C_ / 4);
        int x = pix % WM_, y = pix / WM_;
        int x1 = min(x + 1, WM_ - 1), y1 = min(y + 1, HM_ - 1);
        int i00 = y  * WM_ + x,  i01 = y  * WM_ + x1;
        int i10 = y1 * WM_ + x,  i11 = y1 * WM_ + x1;
        const float* b0 = look + ((size_t)n * C_ + 4 * c4) * HW_;
        const float* b1 = b0 + HW_;
        const float* b2 = b1 + HW_;
        const float* b3 = b2 + HW_;
        uint4 q;
        q.x = pk4_fp8(b0[i00], b1[i00], b2[i00], b3[i00]);
        q.y = pk4_fp8(b0[i01], b1[i01], b2[i01], b3[i01]);
        q.z = pk4_fp8(b0[i10], b1[i10], b2[i10], b3[i10]);
        q.w = pk4_fp8(b0[i11], b1[i11], b2[i11], b3[i11]);
        quad4[t] = q;
    } else {
        int t   = (blk - NQBLK) * 256 + threadIdx.x;   // B*(C/4)*HW
        int pix = t % HW_;
        int rem = t / HW_;
        int c4  = rem % (C_ / 4);
        int b   = rem / (C_ / 4);
        const float* p = cur + ((size_t)b * C_ + 4 * c4) * HW_ + pix;
        H4 h;
        h.a = h2{(half_t)(-p[0]),               (half_t)(-p[(size_t)HW_])};
        h.b = h2{(half_t)(-p[2 * (size_t)HW_]), (half_t)(-p[3 * (size_t)HW_])};
        cur2[t] = h;
    }
}

// ---------------------------------------------------------------------------
// Main cost-volume kernel. One thread per output (b,d,hw); block's 4 waves =
// 4 consecutive depths of the same 64-pixel segment (r8 mapping, keeps the
// L1/L2 cross-depth sharing). Per 4 channels: 3 loads (2x16B fp8 quad + 1x8B
// negcur f16), 16 v_cvt_pk_f32_fp8 unpacks, float2 (v_pk_fma_f32) bilinear
// math chained from negcur, f32 accumulation. 48 loads/thread vs 80 in r10 --
// attacks the L1 data-path (line-delivery) bound identified in r10.
// ---------------------------------------------------------------------------
__global__ __launch_bounds__(256) void cost_volume(
    const uint4* __restrict__ quad4,   // [B*F][C/4][HW]
    const H4* __restrict__ cur2,       // [B][C/4][HW]
    const float* __restrict__ invK,    // [B][16]
    const float* __restrict__ P,       // [B*F][12]
    const float* __restrict__ validF,  // [B*F]
    float* __restrict__ cvOut)         // [B][D][HW]
{
    int blk  = blockIdx.x;             // 5760 = 120 tile64 * (B_*NDG_)
    int tile = blk / (B_ * NDG_);
    int r    = blk % (B_ * NDG_);
    int b    = r / NDG_;
    int dg   = r % NDG_;
    int wave = threadIdx.x >> 6;
    int lane = threadIdx.x & 63;
    int d    = dg * DW_ + wave;
    int hw   = tile * 64 + lane;

    int x = hw % WM_, y = hw / WM_;
    float fx = (float)x, fy = (float)y;

    const float* ik = invK + (size_t)b * 16;
    float rx = ik[0] * fx + ik[1] * fy + ik[2];
    float ry = ik[4] * fx + ik[5] * fy + ik[6];
    float rz = ik[8] * fx + ik[9] * fy + ik[10];

    float depth = 0.1f + (float)d * (19.9f / 95.0f);
    float qx = depth * rx, qy = depth * ry, qz = depth * rz;

    bool inter = (x >= 2 && x <= WM_ - 3 && y >= 2 && y <= HM_ - 3);

    unsigned pixc[F_];
    float wf[F_][4];
    float ff[F_];

    #pragma unroll
    for (int f = 0; f < F_; ++f) {
        const float* Pf = P + (size_t)(b * F_ + f) * 12;
        float cp0 = Pf[0] * qx + Pf[1] * qy + Pf[2]  * qz + Pf[3];
        float cp1 = Pf[4] * qx + Pf[5] * qy + Pf[6]  * qz + Pf[7];
        float cp2 = Pf[8] * qx + Pf[9] * qy + Pf[10] * qz + Pf[11];
        float z  = cp2 + EPS_;
        float gx = cp0 / z, gy = cp1 / z;

        float x0f = floorf(gx), y0f = floorf(gy);
        float wx1 = gx - x0f, wy1 = gy - y0f;
        float wx0 = 1.f - wx1, wy0 = 1.f - wy1;

        int x0 = (int)x0f, y0 = (int)y0f;
        int cx = min(max(x0, 0), WM_ - 1);
        int cy = min(max(y0, 0), HM_ - 1);
        pixc[f] = (unsigned)(cy * WM_ + cx);

        wf[f][0] = wx0 * wy0;
        wf[f][1] = wx1 * wy0;
        wf[f][2] = wx0 * wy1;
        wf[f][3] = wx1 * wy1;

        bool e = (gx >= 2.f) && (gx <= (float)(WM_ - 2)) &&
                 (gy >= 2.f) && (gy <= (float)(HM_ - 2)) && inter;
        ff[f] = (e ? 1.f : 0.f) * validF[b * F_ + f];
    }

    size_t oidx = ((size_t)(b * D_ + d)) * HW_ + hw;

    // Wave-uniform early-out
    if (__ballot(ff[0] > 0.f || ff[1] > 0.f) == 0ull) {
        cvOut[oidx] = 0.f;
        return;
    }

    // broadcast f32 weight pairs (v_pk_fma_f32 operands)
    f2 W00_0 = f2{wf[0][0], wf[0][0]}, W01_0 = f2{wf[0][1], wf[0][1]};
    f2 W10_0 = f2{wf[0][2], wf[0][2]}, W11_0 = f2{wf[0][3], wf[0][3]};
    f2 W00_1 = f2{wf[1][0], wf[1][0]}, W01_1 = f2{wf[1][1], wf[1][1]};
    f2 W10_1 = f2{wf[1][2], wf[1][2]}, W11_1 = f2{wf[1][3], wf[1][3]};

    const char* qbp = (const char*)quad4;
    const char* cbp = (const char*)cur2;
    unsigned oA = ((u32)((b * F_ + 0) * (C_ / 4)) * HW_ + pixc[0]) * 16u;
    unsigned oB = ((u32)((b * F_ + 1) * (C_ / 4)) * HW_ + pixc[1]) * 16u;
    unsigned oc = ((u32)(b * (C_ / 4)) * HW_ + (u32)hw) * 8u;

    f2 sA = f2{0.f, 0.f}, sB = f2{0.f, 0.f};

    #pragma unroll 4
    for (int c4i = 0; c4i < C_ / 4; ++c4i) {
        uint4 qa = *(const uint4*)(qbp + oA); oA += (u32)HW_ * 16u;
        uint4 qb = *(const uint4*)(qbp + oB); oB += (u32)HW_ * 16u;
        H4 cu = *(const H4*)(cbp + oc); oc += (u32)HW_ * 8u;

        f2 nc01; nc01.x = (float)cu.a.x; nc01.y = (float)cu.a.y;
        f2 nc23; nc23.x = (float)cu.b.x; nc23.y = (float)cu.b.y;

        f2 a01 = fp8pk<false>(qa.x) * W00_0 + (fp8pk<false>(qa.y) * W01_0 +
                 (fp8pk<false>(qa.z) * W10_0 + (fp8pk<false>(qa.w) * W11_0 + nc01)));
        f2 a23 = fp8pk<true >(qa.x) * W00_0 + (fp8pk<true >(qa.y) * W01_0 +
                 (fp8pk<true >(qa.z) * W10_0 + (fp8pk<true >(qa.w) * W11_0 + nc23)));
        f2 b01 = fp8pk<false>(qb.x) * W00_1 + (fp8pk<false>(qb.y) * W01_1 +
                 (fp8pk<false>(qb.z) * W10_1 + (fp8pk<false>(qb.w) * W11_1 + nc01)));
        f2 b23 = fp8pk<true >(qb.x) * W00_1 + (fp8pk<true >(qb.y) * W01_1 +
                 (fp8pk<true >(qb.z) * W10_1 + (fp8pk<true >(qb.w) * W11_1 + nc23)));

        sA.x += fabsf(a01.x); sA.y += fabsf(a01.y);
        sA.x += fabsf(a23.x); sA.y += fabsf(a23.y);
        sB.x += fabsf(b01.x); sB.y += fabsf(b01.y);
        sB.x += fabsf(b23.x); sB.y += fabsf(b23.y);
    }

    float s0 = sA.x + sA.y;
    float s1 = sB.x + sB.y;

    float m0 = s0 * (1.0f / 64.0f) * ff[0];
    float m1 = s1 * (1.0f / 64.0f) * ff[1];
    float costsum = m0 + m1;
    float counts  = ((m0 > 0.f) ? 1.f : 0.f) + ((m1 > 0.f) ? 1.f : 0.f);
    float scale = (counts > 1.5f) ? (1.0f / (2.0f + EPS_)) : (1.0f / (1.0f + EPS_));
    cvOut[oidx] = costsum * scale;
}

// ---------------------------------------------------------------------------
// Finalize: per (b,hw), max over D, then write cost / missing.
// (Also overwrites the cur2 stash that lived in the costOut region.)
// ---------------------------------------------------------------------------
__global__ __launch_bounds__(256) void finalize(
    const float* __restrict__ cv,   // [B][D][HW]
    float* __restrict__ cost,       // [B][D][HW]
    float* __restrict__ missing)    // [B][D][HW]
{
    int t = blockIdx.x * blockDim.x + threadIdx.x;
    if (t >= B_ * HW_) return;
    int b = t / HW_, hw = t % HW_;
    const float* src = cv + (size_t)b * D_ * HW_ + hw;

    float mx = 0.f;   // all values >= 0
    for (int d = 0; d < D_; ++d)
        mx = fmaxf(mx, src[(size_t)d * HW_]);

    for (int d = 0; d < D_; ++d) {
        float v = src[(size_t)d * HW_];
        float m = (v == 0.f) ? 1.f : 0.f;
        size_t o = (size_t)b * D_ * HW_ + (size_t)d * HW_ + hw;
        cost[o]    = (m != 0.f) ? mx : v;
        missing[o] = m;
    }
}

// ---------------------------------------------------------------------------
extern "C" void kernel_launch(void* const* d_in, const int* in_sizes, int n_in,
                              void* d_out, int out_size, void* d_ws, size_t ws_size,
                              hipStream_t stream)
{
    const float* current = (const float*)d_in[0];  // [B,C,H,W]
    const float* lookup  = (const float*)d_in[1];  // [B,F,C,H,W]
    const float* poses   = (const float*)d_in[2];  // [B,F,4,4]
    const float* K       = (const float*)d_in[3];  // [B,4,4]
    const float* invK    = (const float*)d_in[4];  // [B,4,4]

    float* out = (float*)d_out;
    float* costOut    = out;                 // [B,D,H,W]
    float* missingOut = out + NTOT;          // [B,D,H,W]
    float* cvOut      = out + 2 * NTOT;      // [B,D,H,W] (pre-fill cost)

    // workspace: params + 7.9 MB fp8 quad buffer
    float* ws     = (float*)d_ws;
    float* Pmat   = ws;                      // B*F*12 = 48 floats
    float* validF = Pmat + B_ * F_ * 12;     // B*F    = 4 floats
    uint4* quad4  = (uint4*)(ws + 64);       // B*F*(C/4)*HW * 16B = 7,864,320 B

    // cur2 stash lives in the costOut region (1.97 MB << 5.9 MB); it is
    // consumed by cost_volume and then overwritten by finalize.
    H4* cur2 = (H4*)costOut;

    const int npack = NQBLK + NCBLK;             // 1920 + 960 = 2880
    hipLaunchKernelGGL(pack_and_setup, dim3(npack), dim3(256), 0, stream,
                       lookup, current, quad4, cur2, poses, K, Pmat, validF);

    const int nblocks = (HW_ / 64) * B_ * NDG_;  // 120 * 48 = 5760
    hipLaunchKernelGGL(cost_volume, dim3(nblocks), dim3(256), 0, stream,
                       quad4, cur2, invK, Pmat, validF, cvOut);

    const int npix = B_ * HW_;                   // 15,360
    hipLaunchKernelGGL(finalize, dim3((npix + 255) / 256), dim3(256), 0, stream,
                       cvOut, costOut, missingOut);
}

// Round 12
// 59.627 us; speedup vs baseline: 3.5821x; 1.2836x over previous
//
#include <hip/hip_runtime.h>
#include <hip/hip_bf16.h>
#include <stdint.h>

#if __has_builtin(__builtin_amdgcn_cvt_pk_f32_fp8) && __has_builtin(__builtin_amdgcn_cvt_pk_fp8_f32)
#define HAS_HW_FP8 1
#else
#define HAS_HW_FP8 0
#include <hip/hip_fp8.h>
#endif

// Problem constants (from reference)
#define B_  2
#define F_  2
#define C_  64
#define D_  96
#define HM_ 48
#define WM_ 160
#define HW_ (HM_ * WM_)                 // 7680
#define NTOT ((size_t)B_ * D_ * HW_)    // 1,474,560 per output tensor
#define EPS_ 1e-7f
#define DW_  4                          // depths per block (one per wave)
#define NDG_ (D_ / DW_)                 // 24 depth groups

typedef _Float16 half_t;
typedef _Float16 h2 __attribute__((ext_vector_type(2)));
typedef float f2 __attribute__((ext_vector_type(2)));
typedef unsigned int u32;

// 8B: NEGATED cur, 4 f16 channels as 2 pairs
struct H4 { h2 a, b; };

// fp8 quad entry (16B): .x=p00, .y=p01, .z=p10, .w=p11; each u32 = 4 channels
// (c0..c3) as e4m3 bytes.

__device__ __forceinline__ u32 pk4_fp8(float a, float b, float c, float d) {
#if HAS_HW_FP8
    int r = __builtin_amdgcn_cvt_pk_fp8_f32(a, b, 0, false);
    r = __builtin_amdgcn_cvt_pk_fp8_f32(c, d, r, true);
    return (u32)r;
#else
    __hip_fp8_e4m3 qa(a), qb(b), qc(c), qd(d);
    return (u32)qa.__x | ((u32)qb.__x << 8) | ((u32)qc.__x << 16) |
           ((u32)qd.__x << 24);
#endif
}

template <bool HI>
__device__ __forceinline__ f2 fp8pk(u32 v) {
#if HAS_HW_FP8
    return __builtin_amdgcn_cvt_pk_f32_fp8((int)v, HI);
#else
    u32 w = HI ? (v >> 16) : v;
    __hip_fp8_e4m3 q0, q1;
    q0.__x = (uint8_t)(w & 0xff);
    q1.__x = (uint8_t)((w >> 8) & 0xff);
    f2 r; r.x = (float)q0; r.y = (float)q1;
    return r;
#endif
}

#define NQBLK4 ((B_ * F_ * (C_/4) * (HW_/4)) / 256)  // 480
#define NCBLK  ((B_ * (C_/4) * HW_) / 256)           // 960

// ---------------------------------------------------------------------------
// Pack:
//  * quad4 [n][C/4][HW] (16B): corner-major fp8 quads, 4 channels per entry.
//    4 pixels per thread: one aligned float4 + 1 scalar per channel-row
//    covers all 4 entries' corners (4 loads/entry vs 16).
//  * cur2  [b][C/4][HW] (8B): 4 NEGATED f16 cur channels
// Block 0 also computes P = (K@T)[:3] and pose validity.
// ---------------------------------------------------------------------------
__global__ __launch_bounds__(256) void pack_and_setup(
    const float* __restrict__ look,   // [B*F*C][HW]
    const float* __restrict__ cur,    // [B*C][HW]
    uint4* __restrict__ quad4,
    H4* __restrict__ cur2,
    const float* __restrict__ poses,
    const float* __restrict__ K,
    float* __restrict__ Pout,         // [B*F][12]
    float* __restrict__ validOut)     // [B*F]
{
    if (blockIdx.x == 0 && threadIdx.x < 64) {
        int t = threadIdx.x;
        if (t < B_ * F_ * 12) {
            int j  = t & 3;
            int i  = (t >> 2) % 3;
            int bf = t / 12;
            int b  = bf / F_;
            const float* Kb = K + (size_t)b * 16;
            const float* T  = poses + (size_t)bf * 16;
            float s = 0.f;
            #pragma unroll
            for (int k = 0; k < 4; ++k) s += Kb[i * 4 + k] * T[k * 4 + j];
            Pout[bf * 12 + i * 4 + j] = s;
        }
        if (t < B_ * F_) {
            const float* T = poses + (size_t)t * 16;
            float s = 0.f;
            #pragma unroll
            for (int k = 0; k < 16; ++k) s += T[k];
            validOut[t] = (s != 0.0f) ? 1.0f : 0.0f;
        }
    }

    int blk = blockIdx.x;
    if (blk < NQBLK4) {
        int t   = blk * 256 + threadIdx.x;     // B*F*(C/4)*(HW/4)
        int g   = t % (HW_ / 4);               // 4-pixel group (same row)
        int rem = t / (HW_ / 4);
        int c4  = rem % (C_ / 4);
        int n   = rem / (C_ / 4);
        int x0 = (g * 4) % WM_;
        int y  = (g * 4) / WM_;
        int y1 = min(y + 1, HM_ - 1);
        int xe = min(x0 + 4, WM_ - 1);

        const float* base = look + ((size_t)n * C_ + 4 * c4) * HW_;
        float4 rA[4], rB[4];
        float  eA[4], eB[4];
        #pragma unroll
        for (int k = 0; k < 4; ++k) {
            const float* bc = base + (size_t)k * HW_;
            rA[k] = *(const float4*)(bc + y  * WM_ + x0);
            eA[k] = bc[y  * WM_ + xe];
            rB[k] = *(const float4*)(bc + y1 * WM_ + x0);
            eB[k] = bc[y1 * WM_ + xe];
        }
        const float* fA[4] = {(const float*)&rA[0], (const float*)&rA[1],
                              (const float*)&rA[2], (const float*)&rA[3]};
        const float* fB[4] = {(const float*)&rB[0], (const float*)&rB[1],
                              (const float*)&rB[2], (const float*)&rB[3]};

        uint4* outp = quad4 + ((size_t)(n * (C_ / 4) + c4)) * HW_ + g * 4;
        #pragma unroll
        for (int j = 0; j < 4; ++j) {
            float p01_0 = (j < 3) ? fA[0][j + 1] : eA[0];
            float p01_1 = (j < 3) ? fA[1][j + 1] : eA[1];
            float p01_2 = (j < 3) ? fA[2][j + 1] : eA[2];
            float p01_3 = (j < 3) ? fA[3][j + 1] : eA[3];
            float p11_0 = (j < 3) ? fB[0][j + 1] : eB[0];
            float p11_1 = (j < 3) ? fB[1][j + 1] : eB[1];
            float p11_2 = (j < 3) ? fB[2][j + 1] : eB[2];
            float p11_3 = (j < 3) ? fB[3][j + 1] : eB[3];
            uint4 q;
            q.x = pk4_fp8(fA[0][j], fA[1][j], fA[2][j], fA[3][j]);
            q.y = pk4_fp8(p01_0,    p01_1,    p01_2,    p01_3);
            q.z = pk4_fp8(fB[0][j], fB[1][j], fB[2][j], fB[3][j]);
            q.w = pk4_fp8(p11_0,    p11_1,    p11_2,    p11_3);
            outp[j] = q;
        }
    } else {
        int t   = (blk - NQBLK4) * 256 + threadIdx.x;  // B*(C/4)*HW
        int pix = t % HW_;
        int rem = t / HW_;
        int c4  = rem % (C_ / 4);
        int b   = rem / (C_ / 4);
        const float* p = cur + ((size_t)b * C_ + 4 * c4) * HW_ + pix;
        H4 h;
        h.a = h2{(half_t)(-p[0]),               (half_t)(-p[(size_t)HW_])};
        h.b = h2{(half_t)(-p[2 * (size_t)HW_]), (half_t)(-p[3 * (size_t)HW_])};
        cur2[t] = h;
    }
}

// ---------------------------------------------------------------------------
// Main cost-volume kernel (UNCHANGED from round 11 -- proven 48.4 us).
// ---------------------------------------------------------------------------
__global__ __launch_bounds__(256) void cost_volume(
    const uint4* __restrict__ quad4,   // [B*F][C/4][HW]
    const H4* __restrict__ cur2,       // [B][C/4][HW]
    const float* __restrict__ invK,    // [B][16]
    const float* __restrict__ P,       // [B*F][12]
    const float* __restrict__ validF,  // [B*F]
    float* __restrict__ cvOut)         // [B][D][HW]
{
    int blk  = blockIdx.x;             // 5760 = 120 tile64 * (B_*NDG_)
    int tile = blk / (B_ * NDG_);
    int r    = blk % (B_ * NDG_);
    int b    = r / NDG_;
    int dg   = r % NDG_;
    int wave = threadIdx.x >> 6;
    int lane = threadIdx.x & 63;
    int d    = dg * DW_ + wave;
    int hw   = tile * 64 + lane;

    int x = hw % WM_, y = hw / WM_;
    float fx = (float)x, fy = (float)y;

    const float* ik = invK + (size_t)b * 16;
    float rx = ik[0] * fx + ik[1] * fy + ik[2];
    float ry = ik[4] * fx + ik[5] * fy + ik[6];
    float rz = ik[8] * fx + ik[9] * fy + ik[10];

    float depth = 0.1f + (float)d * (19.9f / 95.0f);
    float qx = depth * rx, qy = depth * ry, qz = depth * rz;

    bool inter = (x >= 2 && x <= WM_ - 3 && y >= 2 && y <= HM_ - 3);

    unsigned pixc[F_];
    float wf[F_][4];
    float ff[F_];

    #pragma unroll
    for (int f = 0; f < F_; ++f) {
        const float* Pf = P + (size_t)(b * F_ + f) * 12;
        float cp0 = Pf[0] * qx + Pf[1] * qy + Pf[2]  * qz + Pf[3];
        float cp1 = Pf[4] * qx + Pf[5] * qy + Pf[6]  * qz + Pf[7];
        float cp2 = Pf[8] * qx + Pf[9] * qy + Pf[10] * qz + Pf[11];
        float z  = cp2 + EPS_;
        float gx = cp0 / z, gy = cp1 / z;

        float x0f = floorf(gx), y0f = floorf(gy);
        float wx1 = gx - x0f, wy1 = gy - y0f;
        float wx0 = 1.f - wx1, wy0 = 1.f - wy1;

        int x0 = (int)x0f, y0 = (int)y0f;
        int cx = min(max(x0, 0), WM_ - 1);
        int cy = min(max(y0, 0), HM_ - 1);
        pixc[f] = (unsigned)(cy * WM_ + cx);

        wf[f][0] = wx0 * wy0;
        wf[f][1] = wx1 * wy0;
        wf[f][2] = wx0 * wy1;
        wf[f][3] = wx1 * wy1;

        bool e = (gx >= 2.f) && (gx <= (float)(WM_ - 2)) &&
                 (gy >= 2.f) && (gy <= (float)(HM_ - 2)) && inter;
        ff[f] = (e ? 1.f : 0.f) * validF[b * F_ + f];
    }

    size_t oidx = ((size_t)(b * D_ + d)) * HW_ + hw;

    // Wave-uniform early-out
    if (__ballot(ff[0] > 0.f || ff[1] > 0.f) == 0ull) {
        cvOut[oidx] = 0.f;
        return;
    }

    // broadcast f32 weight pairs (v_pk_fma_f32 operands)
    f2 W00_0 = f2{wf[0][0], wf[0][0]}, W01_0 = f2{wf[0][1], wf[0][1]};
    f2 W10_0 = f2{wf[0][2], wf[0][2]}, W11_0 = f2{wf[0][3], wf[0][3]};
    f2 W00_1 = f2{wf[1][0], wf[1][0]}, W01_1 = f2{wf[1][1], wf[1][1]};
    f2 W10_1 = f2{wf[1][2], wf[1][2]}, W11_1 = f2{wf[1][3], wf[1][3]};

    const char* qbp = (const char*)quad4;
    const char* cbp = (const char*)cur2;
    unsigned oA = ((u32)((b * F_ + 0) * (C_ / 4)) * HW_ + pixc[0]) * 16u;
    unsigned oB = ((u32)((b * F_ + 1) * (C_ / 4)) * HW_ + pixc[1]) * 16u;
    unsigned oc = ((u32)(b * (C_ / 4)) * HW_ + (u32)hw) * 8u;

    f2 sA = f2{0.f, 0.f}, sB = f2{0.f, 0.f};

    #pragma unroll 4
    for (int c4i = 0; c4i < C_ / 4; ++c4i) {
        uint4 qa = *(const uint4*)(qbp + oA); oA += (u32)HW_ * 16u;
        uint4 qb = *(const uint4*)(qbp + oB); oB += (u32)HW_ * 16u;
        H4 cu = *(const H4*)(cbp + oc); oc += (u32)HW_ * 8u;

        f2 nc01; nc01.x = (float)cu.a.x; nc01.y = (float)cu.a.y;
        f2 nc23; nc23.x = (float)cu.b.x; nc23.y = (float)cu.b.y;

        f2 a01 = fp8pk<false>(qa.x) * W00_0 + (fp8pk<false>(qa.y) * W01_0 +
                 (fp8pk<false>(qa.z) * W10_0 + (fp8pk<false>(qa.w) * W11_0 + nc01)));
        f2 a23 = fp8pk<true >(qa.x) * W00_0 + (fp8pk<true >(qa.y) * W01_0 +
                 (fp8pk<true >(qa.z) * W10_0 + (fp8pk<true >(qa.w) * W11_0 + nc23)));
        f2 b01 = fp8pk<false>(qb.x) * W00_1 + (fp8pk<false>(qb.y) * W01_1 +
                 (fp8pk<false>(qb.z) * W10_1 + (fp8pk<false>(qb.w) * W11_1 + nc01)));
        f2 b23 = fp8pk<true >(qb.x) * W00_1 + (fp8pk<true >(qb.y) * W01_1 +
                 (fp8pk<true >(qb.z) * W10_1 + (fp8pk<true >(qb.w) * W11_1 + nc23)));

        sA.x += fabsf(a01.x); sA.y += fabsf(a01.y);
        sA.x += fabsf(a23.x); sA.y += fabsf(a23.y);
        sB.x += fabsf(b01.x); sB.y += fabsf(b01.y);
        sB.x += fabsf(b23.x); sB.y += fabsf(b23.y);
    }

    float s0 = sA.x + sA.y;
    float s1 = sB.x + sB.y;

    float m0 = s0 * (1.0f / 64.0f) * ff[0];
    float m1 = s1 * (1.0f / 64.0f) * ff[1];
    float costsum = m0 + m1;
    float counts  = ((m0 > 0.f) ? 1.f : 0.f) + ((m1 > 0.f) ? 1.f : 0.f);
    float scale = (counts > 1.5f) ? (1.0f / (2.0f + EPS_)) : (1.0f / (1.0f + EPS_));
    cvOut[oidx] = costsum * scale;
}

// ---------------------------------------------------------------------------
// Finalize: block = 64 pixels x 4 D-slices (one slice per wave). Each thread
// register-caches its 24 depths (no second read), LDS 4-way max combine,
// coalesced strided writes. 4x the waves of the old version, 24 independent
// loads in flight per thread.
// ---------------------------------------------------------------------------
#define FDS_ 4
#define FDP_ (D_ / FDS_)   // 24

__global__ __launch_bounds__(256) void finalize(
    const float* __restrict__ cv,   // [B][D][HW]
    float* __restrict__ cost,       // [B][D][HW]
    float* __restrict__ missing)    // [B][D][HW]
{
    int slice = threadIdx.x >> 6;         // 0..3 (wave id)
    int lp    = threadIdx.x & 63;
    int p     = blockIdx.x * 64 + lp;     // 0..B*HW-1 (grid exact)
    int b = p / HW_, hw = p % HW_;
    const float* src = cv + (size_t)b * D_ * HW_ + (size_t)slice * FDP_ * HW_ + hw;

    float v[FDP_];
    float mx = 0.f;   // all values >= 0
    #pragma unroll
    for (int i = 0; i < FDP_; ++i) {
        v[i] = src[(size_t)i * HW_];
        mx = fmaxf(mx, v[i]);
    }

    __shared__ float lmax[FDS_][64];
    lmax[slice][lp] = mx;
    __syncthreads();
    mx = fmaxf(fmaxf(lmax[0][lp], lmax[1][lp]),
               fmaxf(lmax[2][lp], lmax[3][lp]));

    size_t obase = (size_t)b * D_ * HW_ + (size_t)slice * FDP_ * HW_ + hw;
    #pragma unroll
    for (int i = 0; i < FDP_; ++i) {
        float val = v[i];
        float m = (val == 0.f) ? 1.f : 0.f;
        size_t o = obase + (size_t)i * HW_;
        cost[o]    = (m != 0.f) ? mx : val;
        missing[o] = m;
    }
}

// ---------------------------------------------------------------------------
extern "C" void kernel_launch(void* const* d_in, const int* in_sizes, int n_in,
                              void* d_out, int out_size, void* d_ws, size_t ws_size,
                              hipStream_t stream)
{
    const float* current = (const float*)d_in[0];  // [B,C,H,W]
    const float* lookup  = (const float*)d_in[1];  // [B,F,C,H,W]
    const float* poses   = (const float*)d_in[2];  // [B,F,4,4]
    const float* K       = (const float*)d_in[3];  // [B,4,4]
    const float* invK    = (const float*)d_in[4];  // [B,4,4]

    float* out = (float*)d_out;
    float* costOut    = out;                 // [B,D,H,W]
    float* missingOut = out + NTOT;          // [B,D,H,W]
    float* cvOut      = out + 2 * NTOT;      // [B,D,H,W] (pre-fill cost)

    // workspace: params + 7.9 MB fp8 quad buffer
    float* ws     = (float*)d_ws;
    float* Pmat   = ws;                      // B*F*12 = 48 floats
    float* validF = Pmat + B_ * F_ * 12;     // B*F    = 4 floats
    uint4* quad4  = (uint4*)(ws + 64);       // B*F*(C/4)*HW * 16B = 7,864,320 B

    // cur2 stash lives in the costOut region (1.97 MB << 5.9 MB); it is
    // consumed by cost_volume and then overwritten by finalize.
    H4* cur2 = (H4*)costOut;

    const int npack = NQBLK4 + NCBLK;            // 480 + 960 = 1440
    hipLaunchKernelGGL(pack_and_setup, dim3(npack), dim3(256), 0, stream,
                       lookup, current, quad4, cur2, poses, K, Pmat, validF);

    const int nblocks = (HW_ / 64) * B_ * NDG_;  // 120 * 48 = 5760
    hipLaunchKernelGGL(cost_volume, dim3(nblocks), dim3(256), 0, stream,
                       quad4, cur2, invK, Pmat, validF, cvOut);

    const int nfin = (B_ * HW_) / 64;            // 240 blocks (256 thr: 64px x 4 slices)
    hipLaunchKernelGGL(finalize, dim3(nfin), dim3(256), 0, stream,
                       cvOut, costOut, missingOut);
}